// Round 6
// baseline (1399.150 us; speedup 1.0000x reference)
//
#include <hip/hip_runtime.h>
#include <hip/hip_bf16.h>

// ---------------------------------------------------------------------------
// JKNet: 3x (bipartite SAGEConv(mean) + BN(eval) + ReLU) -> JK concat -> linear
//        -> log_softmax
// CSR via bucketed counting-sort (no write-amplified scatter), bf16 gather,
// bf16 MFMA GEMMs with fused BN/ReLU and fused log_softmax final layer.
// ---------------------------------------------------------------------------

#define N_DST0 100000
#define N_DST1 50000
#define N_DST2 25000
#define HID 256
#define OUTC 47
#define ENDR 25000
#define DR 128                          // dst nodes per CSR bucket
#define BN_SCALE 0.99999500003749969f   // rsqrt(1 + 1e-5)

typedef __attribute__((ext_vector_type(8))) short short8;
typedef __attribute__((ext_vector_type(4))) float f32x4;

__device__ __forceinline__ unsigned short f2b1(float f) {
    unsigned int u = __float_as_uint(f);
    return (unsigned short)((u + 0x7fffu + ((u >> 16) & 1u)) >> 16);  // RNE
}
__device__ __forceinline__ float b2f_lo(unsigned int v) {
    return __uint_as_float(v << 16);
}
__device__ __forceinline__ float b2f_hi(unsigned int v) {
    return __uint_as_float(v & 0xffff0000u);
}

// ---------------------------------------------------------------------------
// fp32 -> bf16 conversion (n must be a multiple of 4)
// ---------------------------------------------------------------------------
__global__ __launch_bounds__(256) void f2b_kernel(
    const float* __restrict__ in, unsigned short* __restrict__ out, int n)
{
    int i = (blockIdx.x * 256 + threadIdx.x) * 4;
    if (i < n) {
        float4 v = *(const float4*)&in[i];
        uint2 o;
        o.x = (unsigned int)f2b1(v.x) | ((unsigned int)f2b1(v.y) << 16);
        o.y = (unsigned int)f2b1(v.z) | ((unsigned int)f2b1(v.w) << 16);
        *(uint2*)&out[i] = o;
    }
}

// ---------------------------------------------------------------------------
// CSR build: degree histogram + two-level scan
// ---------------------------------------------------------------------------
__global__ __launch_bounds__(256) void deg_count(
    const int* __restrict__ col, int* __restrict__ deg, int E)
{
    int e = blockIdx.x * 256 + threadIdx.x;
    if (e < E) atomicAdd(&deg[col[e]], 1);
}

__global__ __launch_bounds__(256) void scan_local(
    const int* __restrict__ deg, int* __restrict__ excl,
    int* __restrict__ blksum, int n)
{
    __shared__ int tsum[256];
    const int t = threadIdx.x;
    const int base = blockIdx.x * 1024 + t * 4;
    int v[4], s = 0;
#pragma unroll
    for (int j = 0; j < 4; ++j) {
        int idx = base + j;
        v[j] = (idx < n) ? deg[idx] : 0;
        s += v[j];
    }
    tsum[t] = s;
    __syncthreads();
    for (int off = 1; off < 256; off <<= 1) {
        int x = (t >= off) ? tsum[t - off] : 0;
        __syncthreads();
        tsum[t] += x;
        __syncthreads();
    }
    if (t == 255) blksum[blockIdx.x] = tsum[255];
    int run = tsum[t] - s;
#pragma unroll
    for (int j = 0; j < 4; ++j) {
        int idx = base + j;
        if (idx < n) excl[idx] = run;
        run += v[j];
    }
}

__global__ __launch_bounds__(256) void scan_blksum(int* __restrict__ blksum, int nb)
{
    __shared__ int sh[256];
    const int t = threadIdx.x;
    int v = (t < nb) ? blksum[t] : 0;
    sh[t] = v;
    __syncthreads();
    for (int off = 1; off < 256; off <<= 1) {
        int x = (t >= off) ? sh[t - off] : 0;
        __syncthreads();
        sh[t] += x;
        __syncthreads();
    }
    if (t < nb) blksum[t] = sh[t] - v;
}

// excl[i] += block offset; also seed per-bucket partition cursors
__global__ __launch_bounds__(256) void add_offsets(
    int* __restrict__ excl, const int* __restrict__ blkoff,
    int* __restrict__ bcur, int n)
{
    int i = blockIdx.x * 256 + threadIdx.x;
    if (i < n) {
        int v = excl[i] + blkoff[i >> 10];
        excl[i] = v;
        if ((i & (DR - 1)) == 0) bcur[i / DR] = v;
    }
}

// ---------------------------------------------------------------------------
// Pass 3: partition edges into dst-range buckets. part[] shares the CSR's
// index space (bucket b's region = [excl[b*DR], excl[(b+1)*DR))), so bcur
// seeded from excl gives exact, overflow-free placement. Writes advance
// sequentially within each bucket -> no 64B-line write amplification.
// ---------------------------------------------------------------------------
__global__ __launch_bounds__(256) void partition_edges(
    const int* __restrict__ row, const int* __restrict__ col,
    int* __restrict__ bcur, uint2* __restrict__ part, int E)
{
    int e = blockIdx.x * 256 + threadIdx.x;
    if (e < E) {
        int c = col[e];
        int pos = atomicAdd(&bcur[c / DR], 1);
        part[pos] = make_uint2((unsigned)c, (unsigned)row[e]);
    }
}

// ---------------------------------------------------------------------------
// Pass 4: per-bucket CSR fill. One block per bucket; LDS cursors; coalesced
// uint2 reads of the bucket's partition; 4B stores confined to the bucket's
// contiguous ~8KB esrc window (L2-resident).
// ---------------------------------------------------------------------------
__global__ __launch_bounds__(256) void bucket_fill(
    const uint2* __restrict__ part, const int* __restrict__ excl,
    int* __restrict__ esrc, int n_dst, int E)
{
    __shared__ int lcur[DR];
    const int b = blockIdx.x;
    const int d0 = b * DR;
    const int t = threadIdx.x;
    if (t < DR) {
        int d = d0 + t;
        lcur[t] = (d < n_dst) ? excl[d] : E;
    }
    __syncthreads();
    const int wstart = excl[d0];
    const int wend = (d0 + DR < n_dst) ? excl[d0 + DR] : E;
    for (int i = wstart + t; i < wend; i += 256) {
        uint2 e = part[i];
        int pos = atomicAdd(&lcur[(int)e.x - d0], 1);
        esrc[pos] = (int)e.y;
    }
}

// ---------------------------------------------------------------------------
// Gather-mean over bf16 sources -> bf16 agg. One wave per destination node.
// 4-edge unroll for memory-level parallelism.
// ---------------------------------------------------------------------------
template<int LOGK>
__global__ __launch_bounds__(256) void gather_mean(
    const unsigned short* __restrict__ xsrc, const int* __restrict__ esrc,
    const int* __restrict__ start, const int* __restrict__ deg,
    unsigned short* __restrict__ agg, int n_dst)
{
    const int wid = (blockIdx.x * 256 + threadIdx.x) >> 6;
    const int lane = threadIdx.x & 63;
    if (wid >= n_dst) return;
    const int s = start[wid];
    const int d = deg[wid];
    const float inv = 1.0f / (float)max(d, 1);

    if (LOGK == 7) {
        float ax = 0.f, ay = 0.f;
        int i = 0;
        for (; i + 4 <= d; i += 4) {
            int r0 = esrc[s + i + 0], r1 = esrc[s + i + 1];
            int r2 = esrc[s + i + 2], r3 = esrc[s + i + 3];
            unsigned int v0 = *(const unsigned int*)&xsrc[((size_t)r0 << 7) + lane * 2];
            unsigned int v1 = *(const unsigned int*)&xsrc[((size_t)r1 << 7) + lane * 2];
            unsigned int v2 = *(const unsigned int*)&xsrc[((size_t)r2 << 7) + lane * 2];
            unsigned int v3 = *(const unsigned int*)&xsrc[((size_t)r3 << 7) + lane * 2];
            ax += b2f_lo(v0); ay += b2f_hi(v0);
            ax += b2f_lo(v1); ay += b2f_hi(v1);
            ax += b2f_lo(v2); ay += b2f_hi(v2);
            ax += b2f_lo(v3); ay += b2f_hi(v3);
        }
        for (; i < d; ++i) {
            int r0 = esrc[s + i];
            unsigned int v0 = *(const unsigned int*)&xsrc[((size_t)r0 << 7) + lane * 2];
            ax += b2f_lo(v0); ay += b2f_hi(v0);
        }
        ax *= inv; ay *= inv;
        *(unsigned int*)&agg[((size_t)wid << 7) + lane * 2] =
            (unsigned int)f2b1(ax) | ((unsigned int)f2b1(ay) << 16);
    } else {
        float ax = 0.f, ay = 0.f, az = 0.f, aw = 0.f;
        int i = 0;
        for (; i + 4 <= d; i += 4) {
            int r0 = esrc[s + i + 0], r1 = esrc[s + i + 1];
            int r2 = esrc[s + i + 2], r3 = esrc[s + i + 3];
            uint2 v0 = *(const uint2*)&xsrc[((size_t)r0 << 8) + lane * 4];
            uint2 v1 = *(const uint2*)&xsrc[((size_t)r1 << 8) + lane * 4];
            uint2 v2 = *(const uint2*)&xsrc[((size_t)r2 << 8) + lane * 4];
            uint2 v3 = *(const uint2*)&xsrc[((size_t)r3 << 8) + lane * 4];
            ax += b2f_lo(v0.x); ay += b2f_hi(v0.x);
            az += b2f_lo(v0.y); aw += b2f_hi(v0.y);
            ax += b2f_lo(v1.x); ay += b2f_hi(v1.x);
            az += b2f_lo(v1.y); aw += b2f_hi(v1.y);
            ax += b2f_lo(v2.x); ay += b2f_hi(v2.x);
            az += b2f_lo(v2.y); aw += b2f_hi(v2.y);
            ax += b2f_lo(v3.x); ay += b2f_hi(v3.x);
            az += b2f_lo(v3.y); aw += b2f_hi(v3.y);
        }
        for (; i < d; ++i) {
            int r0 = esrc[s + i];
            uint2 v0 = *(const uint2*)&xsrc[((size_t)r0 << 8) + lane * 4];
            ax += b2f_lo(v0.x); ay += b2f_hi(v0.x);
            az += b2f_lo(v0.y); aw += b2f_hi(v0.y);
        }
        ax *= inv; ay *= inv; az *= inv; aw *= inv;
        uint2 o;
        o.x = (unsigned int)f2b1(ax) | ((unsigned int)f2b1(ay) << 16);
        o.y = (unsigned int)f2b1(az) | ((unsigned int)f2b1(aw) << 16);
        *(uint2*)&agg[((size_t)wid << 8) + lane * 4] = o;
    }
}

// ---------------------------------------------------------------------------
// bf16 MFMA GEMM: h = relu((agg.Wl^T + xdst.Wr^T) * BN_SCALE * g + b), bf16 out
// Block: 512 threads = 8 waves (2 M-halves x 4 N-quarters). Tile 128 x 256.
// ---------------------------------------------------------------------------
template<int KH>
__global__ __launch_bounds__(512) void sage_gemm_mfma(
    const unsigned short* __restrict__ aggb, const unsigned short* __restrict__ xdstb,
    const unsigned short* __restrict__ Wlb, const unsigned short* __restrict__ Wrb,
    const float* __restrict__ g, const float* __restrict__ b,
    unsigned short* __restrict__ h, int n_dst)
{
    __shared__ uint4 A_sh[512];    // [m:128][g':4]
    __shared__ uint4 B_sh[1024];   // [n:256][g':4]

    const int tid  = threadIdx.x;
    const int lane = tid & 63;
    const int wv   = tid >> 6;
    const int mh   = wv >> 2;
    const int n0   = (wv & 3) * 64;
    const int m0g  = blockIdx.x * 128;
    const int lrow = lane & 15;
    const int lgrp = lane >> 4;

    f32x4 acc[4][4];
#pragma unroll
    for (int i = 0; i < 4; ++i)
#pragma unroll
        for (int j = 0; j < 4; ++j)
            acc[i][j] = (f32x4){0.f, 0.f, 0.f, 0.f};

    for (int kp = 0; kp < 2 * KH; kp += 32) {
        const unsigned short* Asrc = (kp < KH) ? aggb : xdstb;
        const unsigned short* Bsrc = (kp < KH) ? Wlb : Wrb;
        const int kbase = (kp < KH) ? kp : kp - KH;

        {
            int m = tid >> 2, gq = tid & 3;
            int r = m0g + m;
            uint4 v = {0, 0, 0, 0};
            if (r < n_dst) v = *(const uint4*)&Asrc[(size_t)r * KH + kbase + gq * 8];
            A_sh[m * 4 + (gq ^ ((m >> 1) & 3))] = v;
        }
        {
            int nb_ = tid >> 2, gq = tid & 3;
#pragma unroll
            for (int i2 = 0; i2 < 2; ++i2) {
                int n = nb_ + 128 * i2;
                uint4 v = *(const uint4*)&Bsrc[(size_t)n * KH + kbase + gq * 8];
                B_sh[n * 4 + (gq ^ ((n >> 1) & 3))] = v;
            }
        }
        __syncthreads();

        short8 av[4], bv[4];
#pragma unroll
        for (int mf = 0; mf < 4; ++mf) {
            int m = mh * 64 + mf * 16 + lrow;
            av[mf] = *reinterpret_cast<const short8*>(&A_sh[m * 4 + (lgrp ^ ((m >> 1) & 3))]);
        }
#pragma unroll
        for (int nf = 0; nf < 4; ++nf) {
            int n = n0 + nf * 16 + lrow;
            bv[nf] = *reinterpret_cast<const short8*>(&B_sh[n * 4 + (lgrp ^ ((n >> 1) & 3))]);
        }
#pragma unroll
        for (int mf = 0; mf < 4; ++mf)
#pragma unroll
            for (int nf = 0; nf < 4; ++nf)
                acc[mf][nf] = __builtin_amdgcn_mfma_f32_16x16x32_bf16(
                    av[mf], bv[nf], acc[mf][nf], 0, 0, 0);
        __syncthreads();
    }

    // epilogue: BN + ReLU, bf16 store. C/D: col=lane&15, row=(lane>>4)*4+reg.
#pragma unroll
    for (int nf = 0; nf < 4; ++nf) {
        int n = n0 + nf * 16 + lrow;
        float sc = g[n] * BN_SCALE;
        float bi = b[n];
#pragma unroll
        for (int mf = 0; mf < 4; ++mf) {
            int mbase = m0g + mh * 64 + mf * 16 + lgrp * 4;
#pragma unroll
            for (int r = 0; r < 4; ++r) {
                int m = mbase + r;
                if (m < n_dst) {
                    float vv = fmaxf(acc[mf][nf][r] * sc + bi, 0.f);
                    h[(size_t)m * HID + n] = f2b1(vv);
                }
            }
        }
    }
}

// ---------------------------------------------------------------------------
// Final layer via MFMA: z = [h0|h1|h2][:25000] @ WlinPad.T + blin (N padded
// to 64), fused log_softmax, fp32 out. Tile 128 x 64, 4 waves.
// ---------------------------------------------------------------------------
__global__ __launch_bounds__(256) void final_mfma(
    const unsigned short* __restrict__ h0, const unsigned short* __restrict__ h1,
    const unsigned short* __restrict__ h2, const unsigned short* __restrict__ wlinb,
    const float* __restrict__ blin, float* __restrict__ out)
{
    __shared__ uint4 A_sh[512];   // [m:128][g':4]
    __shared__ uint4 B_sh[256];   // [n:64][g':4]

    const int tid  = threadIdx.x;
    const int lane = tid & 63;
    const int wv   = tid >> 6;
    const int m0g  = blockIdx.x * 128;
    const int lrow = lane & 15;
    const int lgrp = lane >> 4;

    f32x4 acc[2][4];
#pragma unroll
    for (int i = 0; i < 2; ++i)
#pragma unroll
        for (int j = 0; j < 4; ++j)
            acc[i][j] = (f32x4){0.f, 0.f, 0.f, 0.f};

    for (int kp = 0; kp < 768; kp += 32) {
        const int seg = kp >> 8;
        const unsigned short* hs = (seg == 0) ? h0 : (seg == 1) ? h1 : h2;
        const int kseg = kp & 255;

#pragma unroll
        for (int l = 0; l < 2; ++l) {
            int idx = tid + l * 256;
            int m = idx >> 2, gq = idx & 3;
            int r = m0g + m;
            uint4 v = {0, 0, 0, 0};
            if (r < ENDR) v = *(const uint4*)&hs[(size_t)r * HID + kseg + gq * 8];
            A_sh[m * 4 + (gq ^ ((m >> 1) & 3))] = v;
        }
        {
            int n = tid >> 2, gq = tid & 3;
            uint4 v = *(const uint4*)&wlinb[(size_t)n * 768 + kp + gq * 8];
            B_sh[n * 4 + (gq ^ ((n >> 1) & 3))] = v;
        }
        __syncthreads();

        short8 av[2], bv[4];
#pragma unroll
        for (int mf = 0; mf < 2; ++mf) {
            int m = wv * 32 + mf * 16 + lrow;
            av[mf] = *reinterpret_cast<const short8*>(&A_sh[m * 4 + (lgrp ^ ((m >> 1) & 3))]);
        }
#pragma unroll
        for (int nf = 0; nf < 4; ++nf) {
            int n = nf * 16 + lrow;
            bv[nf] = *reinterpret_cast<const short8*>(&B_sh[n * 4 + (lgrp ^ ((n >> 1) & 3))]);
        }
#pragma unroll
        for (int mf = 0; mf < 2; ++mf)
#pragma unroll
            for (int nf = 0; nf < 4; ++nf)
                acc[mf][nf] = __builtin_amdgcn_mfma_f32_16x16x32_bf16(
                    av[mf], bv[nf], acc[mf][nf], 0, 0, 0);
        __syncthreads();
    }

    float bv4[4];
#pragma unroll
    for (int nf = 0; nf < 4; ++nf) {
        int n = nf * 16 + lrow;
        bv4[nf] = (n < OUTC) ? blin[n] : 0.f;
    }

#pragma unroll
    for (int mf = 0; mf < 2; ++mf) {
        float z[4][4];
        float rmax[4], rsum[4];
#pragma unroll
        for (int r = 0; r < 4; ++r) {
            float mx = -INFINITY;
#pragma unroll
            for (int nf = 0; nf < 4; ++nf) {
                int n = nf * 16 + lrow;
                float v = (n < OUTC) ? acc[mf][nf][r] + bv4[nf] : -INFINITY;
                z[r][nf] = v;
                mx = fmaxf(mx, v);
            }
            rmax[r] = mx;
        }
#pragma unroll
        for (int off = 8; off >= 1; off >>= 1)
#pragma unroll
            for (int r = 0; r < 4; ++r)
                rmax[r] = fmaxf(rmax[r], __shfl_xor(rmax[r], off));
#pragma unroll
        for (int r = 0; r < 4; ++r) {
            float s = 0.f;
#pragma unroll
            for (int nf = 0; nf < 4; ++nf)
                s += (z[r][nf] > -INFINITY) ? expf(z[r][nf] - rmax[r]) : 0.f;
            rsum[r] = s;
        }
#pragma unroll
        for (int off = 8; off >= 1; off >>= 1)
#pragma unroll
            for (int r = 0; r < 4; ++r)
                rsum[r] += __shfl_xor(rsum[r], off);

#pragma unroll
        for (int r = 0; r < 4; ++r) {
            int m = m0g + wv * 32 + mf * 16 + lgrp * 4 + r;
            if (m < ENDR) {
                float lg = rmax[r] + logf(rsum[r]);
#pragma unroll
                for (int nf = 0; nf < 4; ++nf) {
                    int n = nf * 16 + lrow;
                    if (n < OUTC) out[(size_t)m * OUTC + n] = z[r][nf] - lg;
                }
            }
        }
    }
}

// ---------------------------------------------------------------------------
extern "C" void kernel_launch(void* const* d_in, const int* in_sizes, int n_in,
                              void* d_out, int out_size, void* d_ws, size_t ws_size,
                              hipStream_t stream)
{
    const float* x    = (const float*)d_in[0];
    const int* rows[3] = {(const int*)d_in[1], (const int*)d_in[3], (const int*)d_in[5]};
    const int* cols[3] = {(const int*)d_in[2], (const int*)d_in[4], (const int*)d_in[6]};
    const float* Wl[3] = {(const float*)d_in[7],  (const float*)d_in[11], (const float*)d_in[15]};
    const float* Wr[3] = {(const float*)d_in[8],  (const float*)d_in[12], (const float*)d_in[16]};
    const float* gs[3] = {(const float*)d_in[9],  (const float*)d_in[13], (const float*)d_in[17]};
    const float* bs[3] = {(const float*)d_in[10], (const float*)d_in[14], (const float*)d_in[18]};
    const float* Wlin = (const float*)d_in[19];
    const float* blin = (const float*)d_in[20];
    float* out = (float*)d_out;

    const int Es[3]   = {in_sizes[1], in_sizes[3], in_sizes[5]};
    const int ndst[3] = {N_DST0, N_DST1, N_DST2};
    const int Ks[3]   = {128, 256, 256};

    // ----- workspace layout (bytes) -----
    // xb    @ 0          : 51,200,000
    // h0b   @ 51200000   : 51,200,000
    // h1b   @ 102400000  : 25,600,000
    // h2b   @ 128000000  : 12,800,000
    // aggb  @ 140800000  : 25,600,000  (ends 166,400,000)
    // wb    @ 166400000  : 655,360
    // wlinb @ 167100032  : 98,304      (ends 167,198,336)
    // ints  @ 167600000  : esrc 1.6M | deg 100k | excl 100k | blkoff | bcur
    // part  @ 175600000  : 1.6M uint2 = 12.8 MB (ends ~188.4 MB)
    char* base = (char*)d_ws;
    unsigned short* xb   = (unsigned short*)(base);
    unsigned short* h0b  = (unsigned short*)(base + 51200000);
    unsigned short* h1b  = (unsigned short*)(base + 102400000);
    unsigned short* h2b  = (unsigned short*)(base + 128000000);
    unsigned short* aggb = (unsigned short*)(base + 140800000);
    unsigned short* wb   = (unsigned short*)(base + 166400000);
    unsigned short* wlinb= (unsigned short*)(base + 167100032);
    int* ibase  = (int*)(base + 167600000);
    int* esrc   = ibase;
    int* deg    = ibase + 1600000;
    int* excl   = ibase + 1700000;
    int* blkoff = ibase + 1800000;
    int* bcur   = ibase + 1801000;
    uint2* part = (uint2*)(base + 175600000);

    unsigned short* Wlb[3] = {wb,          wb + 65536,  wb + 196608};
    unsigned short* Wrb[3] = {wb + 32768,  wb + 131072, wb + 262144};
    const int wsz[3] = {256 * 128, 256 * 256, 256 * 256};

    // ----- convert x and weights to bf16; build padded bf16 Wlin -----
    f2b_kernel<<<(25600000 / 4 + 255) / 256, 256, 0, stream>>>(x, xb, 25600000);
    for (int L = 0; L < 3; ++L) {
        f2b_kernel<<<(wsz[L] / 4 + 255) / 256, 256, 0, stream>>>(Wl[L], Wlb[L], wsz[L]);
        f2b_kernel<<<(wsz[L] / 4 + 255) / 256, 256, 0, stream>>>(Wr[L], Wrb[L], wsz[L]);
    }
    hipMemsetAsync(wlinb, 0, 64 * 768 * sizeof(unsigned short), stream);
    f2b_kernel<<<((OUTC * 768) / 4 + 255) / 256, 256, 0, stream>>>(
        Wlin, wlinb, OUTC * 768);

    const unsigned short* hsrc[3] = {xb, h0b, h1b};
    unsigned short* hdst[3] = {h0b, h1b, h2b};

    for (int L = 0; L < 3; ++L) {
        const int E = Es[L], nd = ndst[L];
        const int nb = (nd + 1023) / 1024;
        const int nbuck = (nd + DR - 1) / DR;
        hipMemsetAsync(deg, 0, (size_t)nd * sizeof(int), stream);
        deg_count<<<(E + 255) / 256, 256, 0, stream>>>(cols[L], deg, E);
        scan_local<<<nb, 256, 0, stream>>>(deg, excl, blkoff, nd);
        scan_blksum<<<1, 256, 0, stream>>>(blkoff, nb);
        add_offsets<<<(nd + 255) / 256, 256, 0, stream>>>(excl, blkoff, bcur, nd);
        partition_edges<<<(E + 255) / 256, 256, 0, stream>>>(
            rows[L], cols[L], bcur, part, E);
        bucket_fill<<<nbuck, 256, 0, stream>>>(part, excl, esrc, nd, E);

        if (Ks[L] == 128) {
            gather_mean<7><<<(nd + 3) / 4, 256, 0, stream>>>(hsrc[L], esrc, excl, deg, aggb, nd);
            sage_gemm_mfma<128><<<(nd + 127) / 128, 512, 0, stream>>>(
                aggb, hsrc[L], Wlb[L], Wrb[L], gs[L], bs[L], hdst[L], nd);
        } else {
            gather_mean<8><<<(nd + 3) / 4, 256, 0, stream>>>(hsrc[L], esrc, excl, deg, aggb, nd);
            sage_gemm_mfma<256><<<(nd + 127) / 128, 512, 0, stream>>>(
                aggb, hsrc[L], Wlb[L], Wrb[L], gs[L], bs[L], hdst[L], nd);
        }
    }

    final_mfma<<<(ENDR + 127) / 128, 256, 0, stream>>>(
        h0b, h1b, h2b, wlinb, blin, out);
}

// Round 7
// 616.916 us; speedup vs baseline: 2.2680x; 2.2680x over previous
//
#include <hip/hip_runtime.h>
#include <hip/hip_bf16.h>

// ---------------------------------------------------------------------------
// JKNet: 3x (bipartite SAGEConv(mean) + BN(eval) + ReLU) -> JK concat -> linear
//        -> log_softmax
// CSR via LDS-staged multisplit (low-contention, write-combined) + bucket fill,
// bf16 gather, bf16 MFMA GEMMs, fused BN/ReLU + fused log_softmax final.
// ---------------------------------------------------------------------------

#define N_DST0 100000
#define N_DST1 50000
#define N_DST2 25000
#define HID 256
#define OUTC 47
#define ENDR 25000
#define DRC 512                         // dst nodes per coarse bucket
#define NBMAX 256                       // max coarse buckets (100000/512=196)
#define CHUNK 8192                      // edges per multisplit block
#define BN_SCALE 0.99999500003749969f   // rsqrt(1 + 1e-5)

typedef __attribute__((ext_vector_type(8))) short short8;
typedef __attribute__((ext_vector_type(4))) float f32x4;

__device__ __forceinline__ unsigned short f2b1(float f) {
    unsigned int u = __float_as_uint(f);
    return (unsigned short)((u + 0x7fffu + ((u >> 16) & 1u)) >> 16);  // RNE
}
__device__ __forceinline__ float b2f_lo(unsigned int v) {
    return __uint_as_float(v << 16);
}
__device__ __forceinline__ float b2f_hi(unsigned int v) {
    return __uint_as_float(v & 0xffff0000u);
}

// ---------------------------------------------------------------------------
// fp32 -> bf16 conversion (n must be a multiple of 4)
// ---------------------------------------------------------------------------
__global__ __launch_bounds__(256) void f2b_kernel(
    const float* __restrict__ in, unsigned short* __restrict__ out, int n)
{
    int i = (blockIdx.x * 256 + threadIdx.x) * 4;
    if (i < n) {
        float4 v = *(const float4*)&in[i];
        uint2 o;
        o.x = (unsigned int)f2b1(v.x) | ((unsigned int)f2b1(v.y) << 16);
        o.y = (unsigned int)f2b1(v.z) | ((unsigned int)f2b1(v.w) << 16);
        *(uint2*)&out[i] = o;
    }
}

// ---------------------------------------------------------------------------
// CSR build: degree histogram + two-level scan
// ---------------------------------------------------------------------------
__global__ __launch_bounds__(256) void deg_count(
    const int* __restrict__ col, int* __restrict__ deg, int E)
{
    int e = blockIdx.x * 256 + threadIdx.x;
    if (e < E) atomicAdd(&deg[col[e]], 1);
}

__global__ __launch_bounds__(256) void scan_local(
    const int* __restrict__ deg, int* __restrict__ excl,
    int* __restrict__ blksum, int n)
{
    __shared__ int tsum[256];
    const int t = threadIdx.x;
    const int base = blockIdx.x * 1024 + t * 4;
    int v[4], s = 0;
#pragma unroll
    for (int j = 0; j < 4; ++j) {
        int idx = base + j;
        v[j] = (idx < n) ? deg[idx] : 0;
        s += v[j];
    }
    tsum[t] = s;
    __syncthreads();
    for (int off = 1; off < 256; off <<= 1) {
        int x = (t >= off) ? tsum[t - off] : 0;
        __syncthreads();
        tsum[t] += x;
        __syncthreads();
    }
    if (t == 255) blksum[blockIdx.x] = tsum[255];
    int run = tsum[t] - s;
#pragma unroll
    for (int j = 0; j < 4; ++j) {
        int idx = base + j;
        if (idx < n) excl[idx] = run;
        run += v[j];
    }
}

__global__ __launch_bounds__(256) void scan_blksum(int* __restrict__ blksum, int nb)
{
    __shared__ int sh[256];
    const int t = threadIdx.x;
    int v = (t < nb) ? blksum[t] : 0;
    sh[t] = v;
    __syncthreads();
    for (int off = 1; off < 256; off <<= 1) {
        int x = (t >= off) ? sh[t - off] : 0;
        __syncthreads();
        sh[t] += x;
        __syncthreads();
    }
    if (t < nb) blksum[t] = sh[t] - v;
}

// excl[i] += block offset; seed per-coarse-bucket cursors (padded 16x: 1/line)
__global__ __launch_bounds__(256) void add_offsets(
    int* __restrict__ excl, const int* __restrict__ blkoff,
    int* __restrict__ bcur, int n)
{
    int i = blockIdx.x * 256 + threadIdx.x;
    if (i < n) {
        int v = excl[i] + blkoff[i >> 10];
        excl[i] = v;
        if ((i & (DRC - 1)) == 0) bcur[(i >> 9) * 16] = v;
    }
}

// ---------------------------------------------------------------------------
// LDS-staged multisplit: partition edges into coarse dst buckets (512 dsts).
// Per block: histogram -> scan -> ONE global atomic per touched bucket ->
// LDS scatter (bucket-ordered) -> flush contiguous segments. Writes are
// full-line, single-CU -> ~1x amplification; global atomics: blocks x buckets.
// ---------------------------------------------------------------------------
__global__ __launch_bounds__(256) void multisplit(
    const int* __restrict__ row, const int* __restrict__ col,
    int* __restrict__ bcur, uint2* __restrict__ part, int E)
{
    __shared__ int hist[NBMAX];
    __shared__ int segoff[NBMAX + 1];
    __shared__ int cur[NBMAX];
    __shared__ int delta[NBMAX];
    __shared__ uint2 stage[CHUNK];

    const int t = threadIdx.x;
    const int base = blockIdx.x * CHUNK;
    const int n = min(CHUNK, E - base);

    // A: LDS histogram over coarse buckets
    hist[t] = 0;
    __syncthreads();
    for (int i = t; i < n; i += 256)
        atomicAdd(&hist[col[base + i] >> 9], 1);
    __syncthreads();

    // B: block scan (Hillis-Steele, 256 wide) -> segoff; reserve global space
    int v = hist[t];
    cur[t] = v;
    __syncthreads();
    for (int off = 1; off < 256; off <<= 1) {
        int x = (t >= off) ? cur[t - off] : 0;
        __syncthreads();
        cur[t] += x;
        __syncthreads();
    }
    segoff[t + 1] = cur[t];
    if (t == 0) segoff[0] = 0;
    __syncthreads();
    int so = segoff[t];
    cur[t] = so;                      // re-seed cursors for scatter
    if (v > 0) {
        int g = atomicAdd(&bcur[t * 16], v);
        delta[t] = g - so;            // global base minus local base
    }
    __syncthreads();

    // C: scatter edges into bucket-ordered LDS staging
    for (int i = t; i < n; i += 256) {
        int c = col[base + i];
        int r = row[base + i];
        int p = atomicAdd(&cur[c >> 9], 1);
        stage[p] = make_uint2((unsigned)c, (unsigned)r);
    }
    __syncthreads();

    // D: flush — consecutive slots of a bucket go to consecutive global addrs
    for (int i = t; i < n; i += 256) {
        uint2 e = stage[i];
        part[delta[e.x >> 9] + i] = e;
    }
}

// ---------------------------------------------------------------------------
// Per-bucket CSR fill: one block per coarse bucket; LDS cursors for 512 dsts;
// coalesced uint2 reads; 4B stores confined to the bucket's ~32KB window.
// ---------------------------------------------------------------------------
__global__ __launch_bounds__(256) void bucket_fill(
    const uint2* __restrict__ part, const int* __restrict__ excl,
    int* __restrict__ esrc, int n_dst, int E)
{
    __shared__ int lcur[DRC];
    const int d0 = blockIdx.x * DRC;
    const int t = threadIdx.x;
    for (int j = t; j < DRC; j += 256) {
        int d = d0 + j;
        lcur[j] = (d < n_dst) ? excl[d] : E;
    }
    __syncthreads();
    const int wstart = excl[d0];
    const int wend = (d0 + DRC < n_dst) ? excl[d0 + DRC] : E;
    for (int i = wstart + t; i < wend; i += 256) {
        uint2 e = part[i];
        int pos = atomicAdd(&lcur[(int)e.x - d0], 1);
        esrc[pos] = (int)e.y;
    }
}

// ---------------------------------------------------------------------------
// Gather-mean over bf16 sources -> bf16 agg. One wave per destination node.
// 4-edge unroll for memory-level parallelism.
// ---------------------------------------------------------------------------
template<int LOGK>
__global__ __launch_bounds__(256) void gather_mean(
    const unsigned short* __restrict__ xsrc, const int* __restrict__ esrc,
    const int* __restrict__ start, const int* __restrict__ deg,
    unsigned short* __restrict__ agg, int n_dst)
{
    const int wid = (blockIdx.x * 256 + threadIdx.x) >> 6;
    const int lane = threadIdx.x & 63;
    if (wid >= n_dst) return;
    const int s = start[wid];
    const int d = deg[wid];
    const float inv = 1.0f / (float)max(d, 1);

    if (LOGK == 7) {
        float ax = 0.f, ay = 0.f;
        int i = 0;
        for (; i + 4 <= d; i += 4) {
            int r0 = esrc[s + i + 0], r1 = esrc[s + i + 1];
            int r2 = esrc[s + i + 2], r3 = esrc[s + i + 3];
            unsigned int v0 = *(const unsigned int*)&xsrc[((size_t)r0 << 7) + lane * 2];
            unsigned int v1 = *(const unsigned int*)&xsrc[((size_t)r1 << 7) + lane * 2];
            unsigned int v2 = *(const unsigned int*)&xsrc[((size_t)r2 << 7) + lane * 2];
            unsigned int v3 = *(const unsigned int*)&xsrc[((size_t)r3 << 7) + lane * 2];
            ax += b2f_lo(v0); ay += b2f_hi(v0);
            ax += b2f_lo(v1); ay += b2f_hi(v1);
            ax += b2f_lo(v2); ay += b2f_hi(v2);
            ax += b2f_lo(v3); ay += b2f_hi(v3);
        }
        for (; i < d; ++i) {
            int r0 = esrc[s + i];
            unsigned int v0 = *(const unsigned int*)&xsrc[((size_t)r0 << 7) + lane * 2];
            ax += b2f_lo(v0); ay += b2f_hi(v0);
        }
        ax *= inv; ay *= inv;
        *(unsigned int*)&agg[((size_t)wid << 7) + lane * 2] =
            (unsigned int)f2b1(ax) | ((unsigned int)f2b1(ay) << 16);
    } else {
        float ax = 0.f, ay = 0.f, az = 0.f, aw = 0.f;
        int i = 0;
        for (; i + 4 <= d; i += 4) {
            int r0 = esrc[s + i + 0], r1 = esrc[s + i + 1];
            int r2 = esrc[s + i + 2], r3 = esrc[s + i + 3];
            uint2 v0 = *(const uint2*)&xsrc[((size_t)r0 << 8) + lane * 4];
            uint2 v1 = *(const uint2*)&xsrc[((size_t)r1 << 8) + lane * 4];
            uint2 v2 = *(const uint2*)&xsrc[((size_t)r2 << 8) + lane * 4];
            uint2 v3 = *(const uint2*)&xsrc[((size_t)r3 << 8) + lane * 4];
            ax += b2f_lo(v0.x); ay += b2f_hi(v0.x);
            az += b2f_lo(v0.y); aw += b2f_hi(v0.y);
            ax += b2f_lo(v1.x); ay += b2f_hi(v1.x);
            az += b2f_lo(v1.y); aw += b2f_hi(v1.y);
            ax += b2f_lo(v2.x); ay += b2f_hi(v2.x);
            az += b2f_lo(v2.y); aw += b2f_hi(v2.y);
            ax += b2f_lo(v3.x); ay += b2f_hi(v3.x);
            az += b2f_lo(v3.y); aw += b2f_hi(v3.y);
        }
        for (; i < d; ++i) {
            int r0 = esrc[s + i];
            uint2 v0 = *(const uint2*)&xsrc[((size_t)r0 << 8) + lane * 4];
            ax += b2f_lo(v0.x); ay += b2f_hi(v0.x);
            az += b2f_lo(v0.y); aw += b2f_hi(v0.y);
        }
        ax *= inv; ay *= inv; az *= inv; aw *= inv;
        uint2 o;
        o.x = (unsigned int)f2b1(ax) | ((unsigned int)f2b1(ay) << 16);
        o.y = (unsigned int)f2b1(az) | ((unsigned int)f2b1(aw) << 16);
        *(uint2*)&agg[((size_t)wid << 8) + lane * 4] = o;
    }
}

// ---------------------------------------------------------------------------
// bf16 MFMA GEMM: h = relu((agg.Wl^T + xdst.Wr^T) * BN_SCALE * g + b), bf16 out
// Block: 512 threads = 8 waves (2 M-halves x 4 N-quarters). Tile 128 x 256.
// ---------------------------------------------------------------------------
template<int KH>
__global__ __launch_bounds__(512) void sage_gemm_mfma(
    const unsigned short* __restrict__ aggb, const unsigned short* __restrict__ xdstb,
    const unsigned short* __restrict__ Wlb, const unsigned short* __restrict__ Wrb,
    const float* __restrict__ g, const float* __restrict__ b,
    unsigned short* __restrict__ h, int n_dst)
{
    __shared__ uint4 A_sh[512];    // [m:128][g':4]
    __shared__ uint4 B_sh[1024];   // [n:256][g':4]

    const int tid  = threadIdx.x;
    const int lane = tid & 63;
    const int wv   = tid >> 6;
    const int mh   = wv >> 2;
    const int n0   = (wv & 3) * 64;
    const int m0g  = blockIdx.x * 128;
    const int lrow = lane & 15;
    const int lgrp = lane >> 4;

    f32x4 acc[4][4];
#pragma unroll
    for (int i = 0; i < 4; ++i)
#pragma unroll
        for (int j = 0; j < 4; ++j)
            acc[i][j] = (f32x4){0.f, 0.f, 0.f, 0.f};

    for (int kp = 0; kp < 2 * KH; kp += 32) {
        const unsigned short* Asrc = (kp < KH) ? aggb : xdstb;
        const unsigned short* Bsrc = (kp < KH) ? Wlb : Wrb;
        const int kbase = (kp < KH) ? kp : kp - KH;

        {
            int m = tid >> 2, gq = tid & 3;
            int r = m0g + m;
            uint4 v = {0, 0, 0, 0};
            if (r < n_dst) v = *(const uint4*)&Asrc[(size_t)r * KH + kbase + gq * 8];
            A_sh[m * 4 + (gq ^ ((m >> 1) & 3))] = v;
        }
        {
            int nb_ = tid >> 2, gq = tid & 3;
#pragma unroll
            for (int i2 = 0; i2 < 2; ++i2) {
                int n = nb_ + 128 * i2;
                uint4 v = *(const uint4*)&Bsrc[(size_t)n * KH + kbase + gq * 8];
                B_sh[n * 4 + (gq ^ ((n >> 1) & 3))] = v;
            }
        }
        __syncthreads();

        short8 av[4], bv[4];
#pragma unroll
        for (int mf = 0; mf < 4; ++mf) {
            int m = mh * 64 + mf * 16 + lrow;
            av[mf] = *reinterpret_cast<const short8*>(&A_sh[m * 4 + (lgrp ^ ((m >> 1) & 3))]);
        }
#pragma unroll
        for (int nf = 0; nf < 4; ++nf) {
            int n = n0 + nf * 16 + lrow;
            bv[nf] = *reinterpret_cast<const short8*>(&B_sh[n * 4 + (lgrp ^ ((n >> 1) & 3))]);
        }
#pragma unroll
        for (int mf = 0; mf < 4; ++mf)
#pragma unroll
            for (int nf = 0; nf < 4; ++nf)
                acc[mf][nf] = __builtin_amdgcn_mfma_f32_16x16x32_bf16(
                    av[mf], bv[nf], acc[mf][nf], 0, 0, 0);
        __syncthreads();
    }

    // epilogue: BN + ReLU, bf16 store. C/D: col=lane&15, row=(lane>>4)*4+reg.
#pragma unroll
    for (int nf = 0; nf < 4; ++nf) {
        int n = n0 + nf * 16 + lrow;
        float sc = g[n] * BN_SCALE;
        float bi = b[n];
#pragma unroll
        for (int mf = 0; mf < 4; ++mf) {
            int mbase = m0g + mh * 64 + mf * 16 + lgrp * 4;
#pragma unroll
            for (int r = 0; r < 4; ++r) {
                int m = mbase + r;
                if (m < n_dst) {
                    float vv = fmaxf(acc[mf][nf][r] * sc + bi, 0.f);
                    h[(size_t)m * HID + n] = f2b1(vv);
                }
            }
        }
    }
}

// ---------------------------------------------------------------------------
// Final layer via MFMA: z = [h0|h1|h2][:25000] @ WlinPad.T + blin (N padded
// to 64), fused log_softmax, fp32 out. Tile 128 x 64, 4 waves.
// ---------------------------------------------------------------------------
__global__ __launch_bounds__(256) void final_mfma(
    const unsigned short* __restrict__ h0, const unsigned short* __restrict__ h1,
    const unsigned short* __restrict__ h2, const unsigned short* __restrict__ wlinb,
    const float* __restrict__ blin, float* __restrict__ out)
{
    __shared__ uint4 A_sh[512];   // [m:128][g':4]
    __shared__ uint4 B_sh[256];   // [n:64][g':4]

    const int tid  = threadIdx.x;
    const int lane = tid & 63;
    const int wv   = tid >> 6;
    const int m0g  = blockIdx.x * 128;
    const int lrow = lane & 15;
    const int lgrp = lane >> 4;

    f32x4 acc[2][4];
#pragma unroll
    for (int i = 0; i < 2; ++i)
#pragma unroll
        for (int j = 0; j < 4; ++j)
            acc[i][j] = (f32x4){0.f, 0.f, 0.f, 0.f};

    for (int kp = 0; kp < 768; kp += 32) {
        const int seg = kp >> 8;
        const unsigned short* hs = (seg == 0) ? h0 : (seg == 1) ? h1 : h2;
        const int kseg = kp & 255;

#pragma unroll
        for (int l = 0; l < 2; ++l) {
            int idx = tid + l * 256;
            int m = idx >> 2, gq = idx & 3;
            int r = m0g + m;
            uint4 v = {0, 0, 0, 0};
            if (r < ENDR) v = *(const uint4*)&hs[(size_t)r * HID + kseg + gq * 8];
            A_sh[m * 4 + (gq ^ ((m >> 1) & 3))] = v;
        }
        {
            int n = tid >> 2, gq = tid & 3;
            uint4 v = *(const uint4*)&wlinb[(size_t)n * 768 + kp + gq * 8];
            B_sh[n * 4 + (gq ^ ((n >> 1) & 3))] = v;
        }
        __syncthreads();

        short8 av[2], bv[4];
#pragma unroll
        for (int mf = 0; mf < 2; ++mf) {
            int m = wv * 32 + mf * 16 + lrow;
            av[mf] = *reinterpret_cast<const short8*>(&A_sh[m * 4 + (lgrp ^ ((m >> 1) & 3))]);
        }
#pragma unroll
        for (int nf = 0; nf < 4; ++nf) {
            int n = nf * 16 + lrow;
            bv[nf] = *reinterpret_cast<const short8*>(&B_sh[n * 4 + (lgrp ^ ((n >> 1) & 3))]);
        }
#pragma unroll
        for (int mf = 0; mf < 2; ++mf)
#pragma unroll
            for (int nf = 0; nf < 4; ++nf)
                acc[mf][nf] = __builtin_amdgcn_mfma_f32_16x16x32_bf16(
                    av[mf], bv[nf], acc[mf][nf], 0, 0, 0);
        __syncthreads();
    }

    float bv4[4];
#pragma unroll
    for (int nf = 0; nf < 4; ++nf) {
        int n = nf * 16 + lrow;
        bv4[nf] = (n < OUTC) ? blin[n] : 0.f;
    }

#pragma unroll
    for (int mf = 0; mf < 2; ++mf) {
        float z[4][4];
        float rmax[4], rsum[4];
#pragma unroll
        for (int r = 0; r < 4; ++r) {
            float mx = -INFINITY;
#pragma unroll
            for (int nf = 0; nf < 4; ++nf) {
                int n = nf * 16 + lrow;
                float v = (n < OUTC) ? acc[mf][nf][r] + bv4[nf] : -INFINITY;
                z[r][nf] = v;
                mx = fmaxf(mx, v);
            }
            rmax[r] = mx;
        }
#pragma unroll
        for (int off = 8; off >= 1; off >>= 1)
#pragma unroll
            for (int r = 0; r < 4; ++r)
                rmax[r] = fmaxf(rmax[r], __shfl_xor(rmax[r], off));
#pragma unroll
        for (int r = 0; r < 4; ++r) {
            float s = 0.f;
#pragma unroll
            for (int nf = 0; nf < 4; ++nf)
                s += (z[r][nf] > -INFINITY) ? expf(z[r][nf] - rmax[r]) : 0.f;
            rsum[r] = s;
        }
#pragma unroll
        for (int off = 8; off >= 1; off >>= 1)
#pragma unroll
            for (int r = 0; r < 4; ++r)
                rsum[r] += __shfl_xor(rsum[r], off);

#pragma unroll
        for (int r = 0; r < 4; ++r) {
            int m = m0g + wv * 32 + mf * 16 + lgrp * 4 + r;
            if (m < ENDR) {
                float lg = rmax[r] + logf(rsum[r]);
#pragma unroll
                for (int nf = 0; nf < 4; ++nf) {
                    int n = nf * 16 + lrow;
                    if (n < OUTC) out[(size_t)m * OUTC + n] = z[r][nf] - lg;
                }
            }
        }
    }
}

// ---------------------------------------------------------------------------
extern "C" void kernel_launch(void* const* d_in, const int* in_sizes, int n_in,
                              void* d_out, int out_size, void* d_ws, size_t ws_size,
                              hipStream_t stream)
{
    const float* x    = (const float*)d_in[0];
    const int* rows[3] = {(const int*)d_in[1], (const int*)d_in[3], (const int*)d_in[5]};
    const int* cols[3] = {(const int*)d_in[2], (const int*)d_in[4], (const int*)d_in[6]};
    const float* Wl[3] = {(const float*)d_in[7],  (const float*)d_in[11], (const float*)d_in[15]};
    const float* Wr[3] = {(const float*)d_in[8],  (const float*)d_in[12], (const float*)d_in[16]};
    const float* gs[3] = {(const float*)d_in[9],  (const float*)d_in[13], (const float*)d_in[17]};
    const float* bs[3] = {(const float*)d_in[10], (const float*)d_in[14], (const float*)d_in[18]};
    const float* Wlin = (const float*)d_in[19];
    const float* blin = (const float*)d_in[20];
    float* out = (float*)d_out;

    const int Es[3]   = {in_sizes[1], in_sizes[3], in_sizes[5]};
    const int ndst[3] = {N_DST0, N_DST1, N_DST2};
    const int Ks[3]   = {128, 256, 256};

    // ----- workspace layout (bytes) -----
    // xb    @ 0          : 51,200,000
    // h0b   @ 51200000   : 51,200,000
    // h1b   @ 102400000  : 25,600,000
    // h2b   @ 128000000  : 12,800,000
    // aggb  @ 140800000  : 25,600,000  (ends 166,400,000)
    // wb    @ 166400000  : 655,360
    // wlinb @ 167100032  : 98,304      (ends 167,198,336)
    // ints  @ 167600000  : esrc 1.6M | deg | excl | blkoff | bcur(padded 16x)
    // part  @ 175600000  : 1.6M uint2 = 12.8 MB
    char* base = (char*)d_ws;
    unsigned short* xb   = (unsigned short*)(base);
    unsigned short* h0b  = (unsigned short*)(base + 51200000);
    unsigned short* h1b  = (unsigned short*)(base + 102400000);
    unsigned short* h2b  = (unsigned short*)(base + 128000000);
    unsigned short* aggb = (unsigned short*)(base + 140800000);
    unsigned short* wb   = (unsigned short*)(base + 166400000);
    unsigned short* wlinb= (unsigned short*)(base + 167100032);
    int* ibase  = (int*)(base + 167600000);
    int* esrc   = ibase;
    int* deg    = ibase + 1600000;
    int* excl   = ibase + 1700000;
    int* blkoff = ibase + 1800000;
    int* bcur   = ibase + 1801024;     // NBMAX*16 ints (padded, 1 counter/line)
    uint2* part = (uint2*)(base + 175600000);

    unsigned short* Wlb[3] = {wb,          wb + 65536,  wb + 196608};
    unsigned short* Wrb[3] = {wb + 32768,  wb + 131072, wb + 262144};
    const int wsz[3] = {256 * 128, 256 * 256, 256 * 256};

    // ----- convert x and weights to bf16; build padded bf16 Wlin -----
    f2b_kernel<<<(25600000 / 4 + 255) / 256, 256, 0, stream>>>(x, xb, 25600000);
    for (int L = 0; L < 3; ++L) {
        f2b_kernel<<<(wsz[L] / 4 + 255) / 256, 256, 0, stream>>>(Wl[L], Wlb[L], wsz[L]);
        f2b_kernel<<<(wsz[L] / 4 + 255) / 256, 256, 0, stream>>>(Wr[L], Wrb[L], wsz[L]);
    }
    hipMemsetAsync(wlinb, 0, 64 * 768 * sizeof(unsigned short), stream);
    f2b_kernel<<<((OUTC * 768) / 4 + 255) / 256, 256, 0, stream>>>(
        Wlin, wlinb, OUTC * 768);

    const unsigned short* hsrc[3] = {xb, h0b, h1b};
    unsigned short* hdst[3] = {h0b, h1b, h2b};

    for (int L = 0; L < 3; ++L) {
        const int E = Es[L], nd = ndst[L];
        const int nb = (nd + 1023) / 1024;
        const int nbuck = (nd + DRC - 1) / DRC;
        hipMemsetAsync(deg, 0, (size_t)nd * sizeof(int), stream);
        deg_count<<<(E + 255) / 256, 256, 0, stream>>>(cols[L], deg, E);
        scan_local<<<nb, 256, 0, stream>>>(deg, excl, blkoff, nd);
        scan_blksum<<<1, 256, 0, stream>>>(blkoff, nb);
        add_offsets<<<(nd + 255) / 256, 256, 0, stream>>>(excl, blkoff, bcur, nd);
        multisplit<<<(E + CHUNK - 1) / CHUNK, 256, 0, stream>>>(
            rows[L], cols[L], bcur, part, E);
        bucket_fill<<<nbuck, 256, 0, stream>>>(part, excl, esrc, nd, E);

        if (Ks[L] == 128) {
            gather_mean<7><<<(nd + 3) / 4, 256, 0, stream>>>(hsrc[L], esrc, excl, deg, aggb, nd);
            sage_gemm_mfma<128><<<(nd + 127) / 128, 512, 0, stream>>>(
                aggb, hsrc[L], Wlb[L], Wrb[L], gs[L], bs[L], hdst[L], nd);
        } else {
            gather_mean<8><<<(nd + 3) / 4, 256, 0, stream>>>(hsrc[L], esrc, excl, deg, aggb, nd);
            sage_gemm_mfma<256><<<(nd + 127) / 128, 512, 0, stream>>>(
                aggb, hsrc[L], Wlb[L], Wrb[L], gs[L], bs[L], hdst[L], nd);
        }
    }

    final_mfma<<<(ENDR + 127) / 128, 256, 0, stream>>>(
        h0b, h1b, h2b, wlinb, blin, out);
}

// Round 8
// 502.223 us; speedup vs baseline: 2.7859x; 1.2284x over previous
//
#include <hip/hip_runtime.h>
#include <hip/hip_bf16.h>

// ---------------------------------------------------------------------------
// JKNet: 3x (bipartite SAGEConv(mean) + BN(eval) + ReLU) -> JK concat -> linear
//        -> log_softmax
// Batched CSR build (multisplit counting sort), 2-row/instr bf16 gather,
// bf16 MFMA GEMMs with fused BN/ReLU and fused log_softmax final layer.
// ---------------------------------------------------------------------------

#define N_DST0 100000
#define N_DST1 50000
#define N_DST2 25000
#define HID 256
#define OUTC 47
#define ENDR 25000
#define DRC 512                         // dst nodes per coarse bucket
#define NBMAX 256                       // max coarse buckets (100000/512=196)
#define CHUNK 8192                      // edges per multisplit block
#define BN_SCALE 0.99999500003749969f   // rsqrt(1 + 1e-5)

#define SEL3(y, a, b, c) ((y) == 0 ? (a) : ((y) == 1 ? (b) : (c)))

typedef __attribute__((ext_vector_type(8))) short short8;
typedef __attribute__((ext_vector_type(4))) float f32x4;

__device__ __forceinline__ unsigned short f2b1(float f) {
    unsigned int u = __float_as_uint(f);
    return (unsigned short)((u + 0x7fffu + ((u >> 16) & 1u)) >> 16);  // RNE
}
__device__ __forceinline__ float b2f_lo(unsigned int v) {
    return __uint_as_float(v << 16);
}
__device__ __forceinline__ float b2f_hi(unsigned int v) {
    return __uint_as_float(v & 0xffff0000u);
}
__device__ __forceinline__ unsigned int pack2(float lo, float hi) {
    return (unsigned int)f2b1(lo) | ((unsigned int)f2b1(hi) << 16);
}

// ---------------------------------------------------------------------------
// fp32 -> bf16 conversion (x input; n multiple of 4)
// ---------------------------------------------------------------------------
__global__ __launch_bounds__(256) void f2b_kernel(
    const float* __restrict__ in, unsigned short* __restrict__ out, int n)
{
    int i = (blockIdx.x * 256 + threadIdx.x) * 4;
    if (i < n) {
        float4 v = *(const float4*)&in[i];
        uint2 o;
        o.x = pack2(v.x, v.y);
        o.y = pack2(v.z, v.w);
        *(uint2*)&out[i] = o;
    }
}

// All 7 weight matrices in one launch. Segment boundaries (elements):
// 0,32768,65536,131072,196608,262144,327680,363776 — all multiples of 4.
__global__ __launch_bounds__(256) void f2b_multi(
    const float* s0, const float* s1, const float* s2, const float* s3,
    const float* s4, const float* s5, const float* s6,
    unsigned short* d0, unsigned short* d1, unsigned short* d2,
    unsigned short* d3, unsigned short* d4, unsigned short* d5,
    unsigned short* d6)
{
    int idx = (blockIdx.x * 256 + threadIdx.x) * 4;
    const float* s; unsigned short* d; int off;
    if (idx < 65536)       { if (idx < 32768)  { s = s0; d = d0; off = 0; }
                             else              { s = s1; d = d1; off = 32768; } }
    else if (idx < 196608) { if (idx < 131072) { s = s2; d = d2; off = 65536; }
                             else              { s = s3; d = d3; off = 131072; } }
    else if (idx < 327680) { if (idx < 262144) { s = s4; d = d4; off = 196608; }
                             else              { s = s5; d = d5; off = 262144; } }
    else if (idx < 363776) { s = s6; d = d6; off = 327680; }
    else return;
    int j = idx - off;
    float4 v = *(const float4*)&s[j];
    uint2 o;
    o.x = pack2(v.x, v.y);
    o.y = pack2(v.z, v.w);
    *(uint2*)&d[j] = o;
}

// ---------------------------------------------------------------------------
// CSR build, batched over the 3 layers via blockIdx.y
// ---------------------------------------------------------------------------
__global__ __launch_bounds__(256) void deg_count_all(
    const int* c0, const int* c1, const int* c2,
    int* g0, int* g1, int* g2, int E0, int E1, int E2)
{
    const int y = blockIdx.y;
    const int* col = SEL3(y, c0, c1, c2);
    int* deg = SEL3(y, g0, g1, g2);
    const int E = SEL3(y, E0, E1, E2);
    int e = blockIdx.x * 256 + threadIdx.x;
    if (e < E) atomicAdd(&deg[col[e]], 1);
}

__global__ __launch_bounds__(256) void scan_local_all(
    const int* g0, const int* g1, const int* g2,
    int* x0, int* x1, int* x2, int* blk, int n0, int n1, int n2)
{
    const int y = blockIdx.y;
    const int* deg = SEL3(y, g0, g1, g2);
    int* excl = SEL3(y, x0, x1, x2);
    int* blksum = blk + y * 128;
    const int n = SEL3(y, n0, n1, n2);

    __shared__ int tsum[256];
    const int t = threadIdx.x;
    const int base = blockIdx.x * 1024 + t * 4;
    int v[4], s = 0;
#pragma unroll
    for (int j = 0; j < 4; ++j) {
        int idx = base + j;
        v[j] = (idx < n) ? deg[idx] : 0;
        s += v[j];
    }
    tsum[t] = s;
    __syncthreads();
    for (int off = 1; off < 256; off <<= 1) {
        int x = (t >= off) ? tsum[t - off] : 0;
        __syncthreads();
        tsum[t] += x;
        __syncthreads();
    }
    if (t == 255) blksum[blockIdx.x] = tsum[255];
    int run = tsum[t] - s;
#pragma unroll
    for (int j = 0; j < 4; ++j) {
        int idx = base + j;
        if (idx < n) excl[idx] = run;
        run += v[j];
    }
}

__global__ __launch_bounds__(256) void scan_blksum_all(
    int* blk, int nb0, int nb1, int nb2)
{
    const int y = blockIdx.x;
    int* blksum = blk + y * 128;
    const int nb = SEL3(y, nb0, nb1, nb2);
    __shared__ int sh[256];
    const int t = threadIdx.x;
    int v = (t < nb) ? blksum[t] : 0;
    sh[t] = v;
    __syncthreads();
    for (int off = 1; off < 256; off <<= 1) {
        int x = (t >= off) ? sh[t - off] : 0;
        __syncthreads();
        sh[t] += x;
        __syncthreads();
    }
    if (t < nb) blksum[t] = sh[t] - v;
}

__global__ __launch_bounds__(256) void add_offsets_all(
    int* x0, int* x1, int* x2, const int* blk, int* bcur,
    int n0, int n1, int n2)
{
    const int y = blockIdx.y;
    int* excl = SEL3(y, x0, x1, x2);
    const int* blkoff = blk + y * 128;
    int* bc = bcur + y * (NBMAX * 16);
    const int n = SEL3(y, n0, n1, n2);
    int i = blockIdx.x * 256 + threadIdx.x;
    if (i < n) {
        int v = excl[i] + blkoff[i >> 10];
        excl[i] = v;
        if ((i & (DRC - 1)) == 0) bc[(i >> 9) * 16] = v;
    }
}

// LDS-staged multisplit (coarse 512-dst buckets), batched over layers.
__global__ __launch_bounds__(256) void multisplit_all(
    const int* r0, const int* r1, const int* r2,
    const int* c0, const int* c1, const int* c2,
    int* bcur, uint2* p0, uint2* p1, uint2* p2, int E0, int E1, int E2)
{
    const int y = blockIdx.y;
    const int E = SEL3(y, E0, E1, E2);
    const int base = blockIdx.x * CHUNK;
    if (base >= E) return;
    const int* row = SEL3(y, r0, r1, r2);
    const int* col = SEL3(y, c0, c1, c2);
    int* bc = bcur + y * (NBMAX * 16);
    uint2* part = SEL3(y, p0, p1, p2);

    __shared__ int hist[NBMAX];
    __shared__ int segoff[NBMAX + 1];
    __shared__ int cur[NBMAX];
    __shared__ int delta[NBMAX];
    __shared__ uint2 stage[CHUNK];

    const int t = threadIdx.x;
    const int n = min(CHUNK, E - base);

    hist[t] = 0;
    __syncthreads();
    for (int i = t; i < n; i += 256)
        atomicAdd(&hist[col[base + i] >> 9], 1);
    __syncthreads();

    int v = hist[t];
    cur[t] = v;
    __syncthreads();
    for (int off = 1; off < 256; off <<= 1) {
        int x = (t >= off) ? cur[t - off] : 0;
        __syncthreads();
        cur[t] += x;
        __syncthreads();
    }
    segoff[t + 1] = cur[t];
    if (t == 0) segoff[0] = 0;
    __syncthreads();
    int so = segoff[t];
    cur[t] = so;
    if (v > 0) {
        int g = atomicAdd(&bc[t * 16], v);
        delta[t] = g - so;
    }
    __syncthreads();

    for (int i = t; i < n; i += 256) {
        int c = col[base + i];
        int r = row[base + i];
        int p = atomicAdd(&cur[c >> 9], 1);
        stage[p] = make_uint2((unsigned)c, (unsigned)r);
    }
    __syncthreads();

    for (int i = t; i < n; i += 256) {
        uint2 e = stage[i];
        part[delta[e.x >> 9] + i] = e;
    }
}

// Per-bucket CSR fill, batched over layers.
__global__ __launch_bounds__(256) void bucket_fill_all(
    const uint2* p0, const uint2* p1, const uint2* p2,
    const int* x0, const int* x1, const int* x2,
    int* s0, int* s1, int* s2, int n0, int n1, int n2,
    int E0, int E1, int E2)
{
    const int y = blockIdx.y;
    const int n_dst = SEL3(y, n0, n1, n2);
    const int d0 = blockIdx.x * DRC;
    if (d0 >= n_dst) return;
    const uint2* part = SEL3(y, p0, p1, p2);
    const int* excl = SEL3(y, x0, x1, x2);
    int* esrc = SEL3(y, s0, s1, s2);
    const int E = SEL3(y, E0, E1, E2);

    __shared__ int lcur[DRC];
    const int t = threadIdx.x;
    for (int j = t; j < DRC; j += 256) {
        int d = d0 + j;
        lcur[j] = (d < n_dst) ? excl[d] : E;
    }
    __syncthreads();
    const int wstart = excl[d0];
    const int wend = (d0 + DRC < n_dst) ? excl[d0 + DRC] : E;
    for (int i = wstart + t; i < wend; i += 256) {
        uint2 e = part[i];
        int pos = atomicAdd(&lcur[(int)e.x - d0], 1);
        esrc[pos] = (int)e.y;
    }
}

// ---------------------------------------------------------------------------
// Gather-mean, 2 rows per load instruction: wave splits 32+32 (sub = edge
// parity); lane owns a 16B (K=256) / 8B (K=128) channel slice. 8 edges in
// flight per unrolled iteration; cross-half shfl_xor merge at the end.
// ---------------------------------------------------------------------------
template<int LOGK>
__global__ __launch_bounds__(256) void gather_mean(
    const unsigned short* __restrict__ xsrc, const int* __restrict__ esrc,
    const int* __restrict__ start, const int* __restrict__ deg,
    unsigned short* __restrict__ agg, int n_dst)
{
    const int wid = (blockIdx.x * 256 + threadIdx.x) >> 6;
    const int lane = threadIdx.x & 63;
    if (wid >= n_dst) return;
    const int sub = lane >> 5;
    const int cl  = lane & 31;
    const int s = start[wid];
    const int d = deg[wid];
    const float inv = 1.0f / (float)max(d, 1);

    if (LOGK == 7) {
        float a0 = 0, a1 = 0, a2 = 0, a3 = 0;
        const size_t coff = (size_t)cl * 4;
        int i = 0;
        for (; i + 8 <= d; i += 8) {
            int e0 = esrc[s + i + 0 + sub], e1 = esrc[s + i + 2 + sub];
            int e2 = esrc[s + i + 4 + sub], e3 = esrc[s + i + 6 + sub];
            uint2 v0 = *(const uint2*)&xsrc[((size_t)e0 << 7) + coff];
            uint2 v1 = *(const uint2*)&xsrc[((size_t)e1 << 7) + coff];
            uint2 v2 = *(const uint2*)&xsrc[((size_t)e2 << 7) + coff];
            uint2 v3 = *(const uint2*)&xsrc[((size_t)e3 << 7) + coff];
            a0 += b2f_lo(v0.x) + b2f_lo(v1.x) + b2f_lo(v2.x) + b2f_lo(v3.x);
            a1 += b2f_hi(v0.x) + b2f_hi(v1.x) + b2f_hi(v2.x) + b2f_hi(v3.x);
            a2 += b2f_lo(v0.y) + b2f_lo(v1.y) + b2f_lo(v2.y) + b2f_lo(v3.y);
            a3 += b2f_hi(v0.y) + b2f_hi(v1.y) + b2f_hi(v2.y) + b2f_hi(v3.y);
        }
        for (; i + 2 <= d; i += 2) {
            int e0 = esrc[s + i + sub];
            uint2 v0 = *(const uint2*)&xsrc[((size_t)e0 << 7) + coff];
            a0 += b2f_lo(v0.x); a1 += b2f_hi(v0.x);
            a2 += b2f_lo(v0.y); a3 += b2f_hi(v0.y);
        }
        if (i < d && sub == 0) {
            int e0 = esrc[s + i];
            uint2 v0 = *(const uint2*)&xsrc[((size_t)e0 << 7) + coff];
            a0 += b2f_lo(v0.x); a1 += b2f_hi(v0.x);
            a2 += b2f_lo(v0.y); a3 += b2f_hi(v0.y);
        }
        a0 += __shfl_xor(a0, 32); a1 += __shfl_xor(a1, 32);
        a2 += __shfl_xor(a2, 32); a3 += __shfl_xor(a3, 32);
        if (sub == 0) {
            uint2 o;
            o.x = pack2(a0 * inv, a1 * inv);
            o.y = pack2(a2 * inv, a3 * inv);
            *(uint2*)&agg[((size_t)wid << 7) + coff] = o;
        }
    } else {
        float a0 = 0, a1 = 0, a2 = 0, a3 = 0, a4 = 0, a5 = 0, a6 = 0, a7 = 0;
        const size_t coff = (size_t)cl * 8;
        int i = 0;
        for (; i + 8 <= d; i += 8) {
            int e0 = esrc[s + i + 0 + sub], e1 = esrc[s + i + 2 + sub];
            int e2 = esrc[s + i + 4 + sub], e3 = esrc[s + i + 6 + sub];
            uint4 v0 = *(const uint4*)&xsrc[((size_t)e0 << 8) + coff];
            uint4 v1 = *(const uint4*)&xsrc[((size_t)e1 << 8) + coff];
            uint4 v2 = *(const uint4*)&xsrc[((size_t)e2 << 8) + coff];
            uint4 v3 = *(const uint4*)&xsrc[((size_t)e3 << 8) + coff];
            a0 += b2f_lo(v0.x) + b2f_lo(v1.x) + b2f_lo(v2.x) + b2f_lo(v3.x);
            a1 += b2f_hi(v0.x) + b2f_hi(v1.x) + b2f_hi(v2.x) + b2f_hi(v3.x);
            a2 += b2f_lo(v0.y) + b2f_lo(v1.y) + b2f_lo(v2.y) + b2f_lo(v3.y);
            a3 += b2f_hi(v0.y) + b2f_hi(v1.y) + b2f_hi(v2.y) + b2f_hi(v3.y);
            a4 += b2f_lo(v0.z) + b2f_lo(v1.z) + b2f_lo(v2.z) + b2f_lo(v3.z);
            a5 += b2f_hi(v0.z) + b2f_hi(v1.z) + b2f_hi(v2.z) + b2f_hi(v3.z);
            a6 += b2f_lo(v0.w) + b2f_lo(v1.w) + b2f_lo(v2.w) + b2f_lo(v3.w);
            a7 += b2f_hi(v0.w) + b2f_hi(v1.w) + b2f_hi(v2.w) + b2f_hi(v3.w);
        }
        for (; i + 2 <= d; i += 2) {
            int e0 = esrc[s + i + sub];
            uint4 v0 = *(const uint4*)&xsrc[((size_t)e0 << 8) + coff];
            a0 += b2f_lo(v0.x); a1 += b2f_hi(v0.x);
            a2 += b2f_lo(v0.y); a3 += b2f_hi(v0.y);
            a4 += b2f_lo(v0.z); a5 += b2f_hi(v0.z);
            a6 += b2f_lo(v0.w); a7 += b2f_hi(v0.w);
        }
        if (i < d && sub == 0) {
            int e0 = esrc[s + i];
            uint4 v0 = *(const uint4*)&xsrc[((size_t)e0 << 8) + coff];
            a0 += b2f_lo(v0.x); a1 += b2f_hi(v0.x);
            a2 += b2f_lo(v0.y); a3 += b2f_hi(v0.y);
            a4 += b2f_lo(v0.z); a5 += b2f_hi(v0.z);
            a6 += b2f_lo(v0.w); a7 += b2f_hi(v0.w);
        }
        a0 += __shfl_xor(a0, 32); a1 += __shfl_xor(a1, 32);
        a2 += __shfl_xor(a2, 32); a3 += __shfl_xor(a3, 32);
        a4 += __shfl_xor(a4, 32); a5 += __shfl_xor(a5, 32);
        a6 += __shfl_xor(a6, 32); a7 += __shfl_xor(a7, 32);
        if (sub == 0) {
            uint4 o;
            o.x = pack2(a0 * inv, a1 * inv);
            o.y = pack2(a2 * inv, a3 * inv);
            o.z = pack2(a4 * inv, a5 * inv);
            o.w = pack2(a6 * inv, a7 * inv);
            *(uint4*)&agg[((size_t)wid << 8) + coff] = o;
        }
    }
}

// ---------------------------------------------------------------------------
// bf16 MFMA GEMM: h = relu((agg.Wl^T + xdst.Wr^T) * BN_SCALE * g + b), bf16 out
// Block: 512 threads = 8 waves (2 M-halves x 4 N-quarters). Tile 128 x 256.
// ---------------------------------------------------------------------------
template<int KH>
__global__ __launch_bounds__(512) void sage_gemm_mfma(
    const unsigned short* __restrict__ aggb, const unsigned short* __restrict__ xdstb,
    const unsigned short* __restrict__ Wlb, const unsigned short* __restrict__ Wrb,
    const float* __restrict__ g, const float* __restrict__ b,
    unsigned short* __restrict__ h, int n_dst)
{
    __shared__ uint4 A_sh[512];    // [m:128][g':4]
    __shared__ uint4 B_sh[1024];   // [n:256][g':4]

    const int tid  = threadIdx.x;
    const int lane = tid & 63;
    const int wv   = tid >> 6;
    const int mh   = wv >> 2;
    const int n0   = (wv & 3) * 64;
    const int m0g  = blockIdx.x * 128;
    const int lrow = lane & 15;
    const int lgrp = lane >> 4;

    f32x4 acc[4][4];
#pragma unroll
    for (int i = 0; i < 4; ++i)
#pragma unroll
        for (int j = 0; j < 4; ++j)
            acc[i][j] = (f32x4){0.f, 0.f, 0.f, 0.f};

    for (int kp = 0; kp < 2 * KH; kp += 32) {
        const unsigned short* Asrc = (kp < KH) ? aggb : xdstb;
        const unsigned short* Bsrc = (kp < KH) ? Wlb : Wrb;
        const int kbase = (kp < KH) ? kp : kp - KH;

        {
            int m = tid >> 2, gq = tid & 3;
            int r = m0g + m;
            uint4 v = {0, 0, 0, 0};
            if (r < n_dst) v = *(const uint4*)&Asrc[(size_t)r * KH + kbase + gq * 8];
            A_sh[m * 4 + (gq ^ ((m >> 1) & 3))] = v;
        }
        {
            int nb_ = tid >> 2, gq = tid & 3;
#pragma unroll
            for (int i2 = 0; i2 < 2; ++i2) {
                int n = nb_ + 128 * i2;
                uint4 v = *(const uint4*)&Bsrc[(size_t)n * KH + kbase + gq * 8];
                B_sh[n * 4 + (gq ^ ((n >> 1) & 3))] = v;
            }
        }
        __syncthreads();

        short8 av[4], bv[4];
#pragma unroll
        for (int mf = 0; mf < 4; ++mf) {
            int m = mh * 64 + mf * 16 + lrow;
            av[mf] = *reinterpret_cast<const short8*>(&A_sh[m * 4 + (lgrp ^ ((m >> 1) & 3))]);
        }
#pragma unroll
        for (int nf = 0; nf < 4; ++nf) {
            int n = n0 + nf * 16 + lrow;
            bv[nf] = *reinterpret_cast<const short8*>(&B_sh[n * 4 + (lgrp ^ ((n >> 1) & 3))]);
        }
#pragma unroll
        for (int mf = 0; mf < 4; ++mf)
#pragma unroll
            for (int nf = 0; nf < 4; ++nf)
                acc[mf][nf] = __builtin_amdgcn_mfma_f32_16x16x32_bf16(
                    av[mf], bv[nf], acc[mf][nf], 0, 0, 0);
        __syncthreads();
    }

    // epilogue: BN + ReLU, bf16 store. C/D: col=lane&15, row=(lane>>4)*4+reg.
#pragma unroll
    for (int nf = 0; nf < 4; ++nf) {
        int n = n0 + nf * 16 + lrow;
        float sc = g[n] * BN_SCALE;
        float bi = b[n];
#pragma unroll
        for (int mf = 0; mf < 4; ++mf) {
            int mbase = m0g + mh * 64 + mf * 16 + lgrp * 4;
#pragma unroll
            for (int r = 0; r < 4; ++r) {
                int m = mbase + r;
                if (m < n_dst) {
                    float vv = fmaxf(acc[mf][nf][r] * sc + bi, 0.f);
                    h[(size_t)m * HID + n] = f2b1(vv);
                }
            }
        }
    }
}

// ---------------------------------------------------------------------------
// Final layer via MFMA: z = [h0|h1|h2][:25000] @ WlinPad.T + blin (N padded
// to 64), fused log_softmax, fp32 out. Tile 128 x 64, 4 waves.
// ---------------------------------------------------------------------------
__global__ __launch_bounds__(256) void final_mfma(
    const unsigned short* __restrict__ h0, const unsigned short* __restrict__ h1,
    const unsigned short* __restrict__ h2, const unsigned short* __restrict__ wlinb,
    const float* __restrict__ blin, float* __restrict__ out)
{
    __shared__ uint4 A_sh[512];   // [m:128][g':4]
    __shared__ uint4 B_sh[256];   // [n:64][g':4]

    const int tid  = threadIdx.x;
    const int lane = tid & 63;
    const int wv   = tid >> 6;
    const int m0g  = blockIdx.x * 128;
    const int lrow = lane & 15;
    const int lgrp = lane >> 4;

    f32x4 acc[2][4];
#pragma unroll
    for (int i = 0; i < 2; ++i)
#pragma unroll
        for (int j = 0; j < 4; ++j)
            acc[i][j] = (f32x4){0.f, 0.f, 0.f, 0.f};

    for (int kp = 0; kp < 768; kp += 32) {
        const int seg = kp >> 8;
        const unsigned short* hs = (seg == 0) ? h0 : (seg == 1) ? h1 : h2;
        const int kseg = kp & 255;

#pragma unroll
        for (int l = 0; l < 2; ++l) {
            int idx = tid + l * 256;
            int m = idx >> 2, gq = idx & 3;
            int r = m0g + m;
            uint4 v = {0, 0, 0, 0};
            if (r < ENDR) v = *(const uint4*)&hs[(size_t)r * HID + kseg + gq * 8];
            A_sh[m * 4 + (gq ^ ((m >> 1) & 3))] = v;
        }
        {
            int n = tid >> 2, gq = tid & 3;
            uint4 v = *(const uint4*)&wlinb[(size_t)n * 768 + kp + gq * 8];
            B_sh[n * 4 + (gq ^ ((n >> 1) & 3))] = v;
        }
        __syncthreads();

        short8 av[2], bv[4];
#pragma unroll
        for (int mf = 0; mf < 2; ++mf) {
            int m = wv * 32 + mf * 16 + lrow;
            av[mf] = *reinterpret_cast<const short8*>(&A_sh[m * 4 + (lgrp ^ ((m >> 1) & 3))]);
        }
#pragma unroll
        for (int nf = 0; nf < 4; ++nf) {
            int n = nf * 16 + lrow;
            bv[nf] = *reinterpret_cast<const short8*>(&B_sh[n * 4 + (lgrp ^ ((n >> 1) & 3))]);
        }
#pragma unroll
        for (int mf = 0; mf < 2; ++mf)
#pragma unroll
            for (int nf = 0; nf < 4; ++nf)
                acc[mf][nf] = __builtin_amdgcn_mfma_f32_16x16x32_bf16(
                    av[mf], bv[nf], acc[mf][nf], 0, 0, 0);
        __syncthreads();
    }

    float bv4[4];
#pragma unroll
    for (int nf = 0; nf < 4; ++nf) {
        int n = nf * 16 + lrow;
        bv4[nf] = (n < OUTC) ? blin[n] : 0.f;
    }

#pragma unroll
    for (int mf = 0; mf < 2; ++mf) {
        float z[4][4];
        float rmax[4], rsum[4];
#pragma unroll
        for (int r = 0; r < 4; ++r) {
            float mx = -INFINITY;
#pragma unroll
            for (int nf = 0; nf < 4; ++nf) {
                int n = nf * 16 + lrow;
                float v = (n < OUTC) ? acc[mf][nf][r] + bv4[nf] : -INFINITY;
                z[r][nf] = v;
                mx = fmaxf(mx, v);
            }
            rmax[r] = mx;
        }
#pragma unroll
        for (int off = 8; off >= 1; off >>= 1)
#pragma unroll
            for (int r = 0; r < 4; ++r)
                rmax[r] = fmaxf(rmax[r], __shfl_xor(rmax[r], off));
#pragma unroll
        for (int r = 0; r < 4; ++r) {
            float s = 0.f;
#pragma unroll
            for (int nf = 0; nf < 4; ++nf)
                s += (z[r][nf] > -INFINITY) ? expf(z[r][nf] - rmax[r]) : 0.f;
            rsum[r] = s;
        }
#pragma unroll
        for (int off = 8; off >= 1; off >>= 1)
#pragma unroll
            for (int r = 0; r < 4; ++r)
                rsum[r] += __shfl_xor(rsum[r], off);

#pragma unroll
        for (int r = 0; r < 4; ++r) {
            int m = m0g + wv * 32 + mf * 16 + lgrp * 4 + r;
            if (m < ENDR) {
                float lg = rmax[r] + logf(rsum[r]);
#pragma unroll
                for (int nf = 0; nf < 4; ++nf) {
                    int n = nf * 16 + lrow;
                    if (n < OUTC) out[(size_t)m * OUTC + n] = z[r][nf] - lg;
                }
            }
        }
    }
}

// ---------------------------------------------------------------------------
extern "C" void kernel_launch(void* const* d_in, const int* in_sizes, int n_in,
                              void* d_out, int out_size, void* d_ws, size_t ws_size,
                              hipStream_t stream)
{
    const float* x    = (const float*)d_in[0];
    const int* rows[3] = {(const int*)d_in[1], (const int*)d_in[3], (const int*)d_in[5]};
    const int* cols[3] = {(const int*)d_in[2], (const int*)d_in[4], (const int*)d_in[6]};
    const float* Wl[3] = {(const float*)d_in[7],  (const float*)d_in[11], (const float*)d_in[15]};
    const float* Wr[3] = {(const float*)d_in[8],  (const float*)d_in[12], (const float*)d_in[16]};
    const float* gs[3] = {(const float*)d_in[9],  (const float*)d_in[13], (const float*)d_in[17]};
    const float* bs[3] = {(const float*)d_in[10], (const float*)d_in[14], (const float*)d_in[18]};
    const float* Wlin = (const float*)d_in[19];
    const float* blin = (const float*)d_in[20];
    float* out = (float*)d_out;

    const int E0 = in_sizes[1], E1 = in_sizes[3], E2 = in_sizes[5];

    // ----- workspace layout (bytes) -----
    // xb    @ 0          : 51,200,000
    // h0b   @ 51200000   : 51,200,000
    // h1b   @ 102400000  : 25,600,000
    // h2b   @ 128000000  : 12,800,000
    // aggb  @ 140800000  : 25,600,000  (ends 166,400,000)
    // wb    @ 166400000  : 655,360
    // wlinb @ 167100032  : 98,304      (ends 167,198,336)
    // ints  @ 167600000  : esrc0/1/2 | deg0/1/2 | excl0/1/2 | blkoff | bcur
    // part0 @ 181000000  : 12.8 MB; part1 @ 193800000: 6.4; part2 @ 200200000: 3.2
    char* base = (char*)d_ws;
    unsigned short* xb   = (unsigned short*)(base);
    unsigned short* h0b  = (unsigned short*)(base + 51200000);
    unsigned short* h1b  = (unsigned short*)(base + 102400000);
    unsigned short* h2b  = (unsigned short*)(base + 128000000);
    unsigned short* aggb = (unsigned short*)(base + 140800000);
    unsigned short* wb   = (unsigned short*)(base + 166400000);
    unsigned short* wlinb= (unsigned short*)(base + 167100032);
    int* ibase = (int*)(base + 167600000);
    int* esrc0 = ibase;                 // 1.6M
    int* esrc1 = ibase + 1600000;       // 0.8M
    int* esrc2 = ibase + 2400000;       // 0.4M
    int* deg0  = ibase + 2800000;       // 100k  (deg block contiguous: 175k)
    int* deg1  = ibase + 2900000;       // 50k
    int* deg2  = ibase + 2950000;       // 25k
    int* excl0 = ibase + 3000000;
    int* excl1 = ibase + 3100000;
    int* excl2 = ibase + 3150000;
    int* blkoff= ibase + 3200000;       // 3*128
    int* bcur  = ibase + 3201024;       // 3*NBMAX*16 = 12288
    uint2* part0 = (uint2*)(base + 181000000);
    uint2* part1 = (uint2*)(base + 193800000);
    uint2* part2 = (uint2*)(base + 200200000);

    unsigned short* Wlb[3] = {wb,          wb + 65536,  wb + 196608};
    unsigned short* Wrb[3] = {wb + 32768,  wb + 131072, wb + 262144};

    // ----- dtype conversions (3 launches total) -----
    f2b_kernel<<<(25600000 / 4 + 255) / 256, 256, 0, stream>>>(x, xb, 25600000);
    hipMemsetAsync(wlinb, 0, 64 * 768 * sizeof(unsigned short), stream);
    f2b_multi<<<356, 256, 0, stream>>>(
        Wl[0], Wr[0], Wl[1], Wr[1], Wl[2], Wr[2], Wlin,
        Wlb[0], Wrb[0], Wlb[1], Wrb[1], Wlb[2], Wrb[2], wlinb);

    // ----- batched CSR build for all 3 layers (6 launches + 1 memset) -----
    hipMemsetAsync(deg0, 0, 175000 * sizeof(int), stream);
    {
        dim3 gdeg((E0 + 255) / 256, 3);
        deg_count_all<<<gdeg, 256, 0, stream>>>(
            cols[0], cols[1], cols[2], deg0, deg1, deg2, E0, E1, E2);
        dim3 gscan((N_DST0 + 1023) / 1024, 3);
        scan_local_all<<<gscan, 256, 0, stream>>>(
            deg0, deg1, deg2, excl0, excl1, excl2, blkoff,
            N_DST0, N_DST1, N_DST2);
        scan_blksum_all<<<3, 256, 0, stream>>>(
            blkoff, (N_DST0 + 1023) / 1024, (N_DST1 + 1023) / 1024,
            (N_DST2 + 1023) / 1024);
        dim3 gadd((N_DST0 + 255) / 256, 3);
        add_offsets_all<<<gadd, 256, 0, stream>>>(
            excl0, excl1, excl2, blkoff, bcur, N_DST0, N_DST1, N_DST2);
        dim3 gms((E0 + CHUNK - 1) / CHUNK, 3);
        multisplit_all<<<gms, 256, 0, stream>>>(
            rows[0], rows[1], rows[2], cols[0], cols[1], cols[2],
            bcur, part0, part1, part2, E0, E1, E2);
        dim3 gbf((N_DST0 + DRC - 1) / DRC, 3);
        bucket_fill_all<<<gbf, 256, 0, stream>>>(
            part0, part1, part2, excl0, excl1, excl2,
            esrc0, esrc1, esrc2, N_DST0, N_DST1, N_DST2, E0, E1, E2);
    }

    // ----- 3 layers: gather + fused GEMM -----
    const unsigned short* hsrc[3] = {xb, h0b, h1b};
    unsigned short* hdst[3] = {h0b, h1b, h2b};
    int* esrcs[3] = {esrc0, esrc1, esrc2};
    int* excls[3] = {excl0, excl1, excl2};
    int* degs[3]  = {deg0, deg1, deg2};
    const int ndst[3] = {N_DST0, N_DST1, N_DST2};

    for (int L = 0; L < 3; ++L) {
        const int nd = ndst[L];
        if (L == 0) {
            gather_mean<7><<<(nd + 3) / 4, 256, 0, stream>>>(
                hsrc[L], esrcs[L], excls[L], degs[L], aggb, nd);
            sage_gemm_mfma<128><<<(nd + 127) / 128, 512, 0, stream>>>(
                aggb, hsrc[L], Wlb[L], Wrb[L], gs[L], bs[L], hdst[L], nd);
        } else {
            gather_mean<8><<<(nd + 3) / 4, 256, 0, stream>>>(
                hsrc[L], esrcs[L], excls[L], degs[L], aggb, nd);
            sage_gemm_mfma<256><<<(nd + 127) / 128, 512, 0, stream>>>(
                aggb, hsrc[L], Wlb[L], Wrb[L], gs[L], bs[L], hdst[L], nd);
        }
    }

    final_mfma<<<(ENDR + 127) / 128, 256, 0, stream>>>(
        h0b, h1b, h2b, wlinb, blin, out);
}

// Round 9
// 406.090 us; speedup vs baseline: 3.4454x; 1.2367x over previous
//
#include <hip/hip_runtime.h>
#include <hip/hip_bf16.h>

// ---------------------------------------------------------------------------
// JKNet: 3x (bipartite SAGEConv(mean) + BN(eval) + ReLU) -> JK concat -> linear
//        -> log_softmax
// CSR via bucket-hist + multisplit counting sort (all dst-granular work in
// LDS; no global random atomics), 2-row/instr bf16 gather, bf16 MFMA GEMMs
// with fused BN/ReLU and fused log_softmax final layer.
// ---------------------------------------------------------------------------

#define N_DST0 100000
#define N_DST1 50000
#define N_DST2 25000
#define HID 256
#define OUTC 47
#define ENDR 25000
#define DRC 512                         // dst nodes per coarse bucket
#define NBMAX 256                       // max coarse buckets (100000/512=196)
#define CHUNK 8192                      // edges per multisplit block
#define BN_SCALE 0.99999500003749969f   // rsqrt(1 + 1e-5)

#define SEL3(y, a, b, c) ((y) == 0 ? (a) : ((y) == 1 ? (b) : (c)))

typedef __attribute__((ext_vector_type(8))) short short8;
typedef __attribute__((ext_vector_type(4))) float f32x4;

__device__ __forceinline__ unsigned short f2b1(float f) {
    unsigned int u = __float_as_uint(f);
    return (unsigned short)((u + 0x7fffu + ((u >> 16) & 1u)) >> 16);  // RNE
}
__device__ __forceinline__ float b2f_lo(unsigned int v) {
    return __uint_as_float(v << 16);
}
__device__ __forceinline__ float b2f_hi(unsigned int v) {
    return __uint_as_float(v & 0xffff0000u);
}
__device__ __forceinline__ unsigned int pack2(float lo, float hi) {
    return (unsigned int)f2b1(lo) | ((unsigned int)f2b1(hi) << 16);
}

// ---------------------------------------------------------------------------
// fp32 -> bf16 conversion (x input; n multiple of 4)
// ---------------------------------------------------------------------------
__global__ __launch_bounds__(256) void f2b_kernel(
    const float* __restrict__ in, unsigned short* __restrict__ out, int n)
{
    int i = (blockIdx.x * 256 + threadIdx.x) * 4;
    if (i < n) {
        float4 v = *(const float4*)&in[i];
        uint2 o;
        o.x = pack2(v.x, v.y);
        o.y = pack2(v.z, v.w);
        *(uint2*)&out[i] = o;
    }
}

// All 7 weight matrices in one launch. Segment boundaries (elements):
// 0,32768,65536,131072,196608,262144,327680,363776 — all multiples of 4.
__global__ __launch_bounds__(256) void f2b_multi(
    const float* s0, const float* s1, const float* s2, const float* s3,
    const float* s4, const float* s5, const float* s6,
    unsigned short* d0, unsigned short* d1, unsigned short* d2,
    unsigned short* d3, unsigned short* d4, unsigned short* d5,
    unsigned short* d6)
{
    int idx = (blockIdx.x * 256 + threadIdx.x) * 4;
    const float* s; unsigned short* d; int off;
    if (idx < 65536)       { if (idx < 32768)  { s = s0; d = d0; off = 0; }
                             else              { s = s1; d = d1; off = 32768; } }
    else if (idx < 196608) { if (idx < 131072) { s = s2; d = d2; off = 65536; }
                             else              { s = s3; d = d3; off = 131072; } }
    else if (idx < 327680) { if (idx < 262144) { s = s4; d = d4; off = 196608; }
                             else              { s = s5; d = d5; off = 262144; } }
    else if (idx < 363776) { s = s6; d = d6; off = 327680; }
    else return;
    int j = idx - off;
    float4 v = *(const float4*)&s[j];
    uint2 o;
    o.x = pack2(v.x, v.y);
    o.y = pack2(v.z, v.w);
    *(uint2*)&d[j] = o;
}

// ---------------------------------------------------------------------------
// Stage 1: coarse-bucket histogram. LDS histogram per block; one padded
// global atomic per (block, nonzero bucket). bhist counters padded 16x.
// ---------------------------------------------------------------------------
__global__ __launch_bounds__(256) void bucket_hist_all(
    const int* c0, const int* c1, const int* c2,
    int* __restrict__ bhist, int E0, int E1, int E2)
{
    const int y = blockIdx.y;
    const int* col = SEL3(y, c0, c1, c2);
    const int E = SEL3(y, E0, E1, E2);
    __shared__ int h[NBMAX];
    const int t = threadIdx.x;
    h[t] = 0;
    __syncthreads();
    const int stride = gridDim.x * 256;
    for (int i = blockIdx.x * 256 + t; i < E; i += stride)
        atomicAdd(&h[col[i] >> 9], 1);
    __syncthreads();
    int v = h[t];
    if (v) atomicAdd(&bhist[(y * NBMAX + t) * 16], v);
}

// ---------------------------------------------------------------------------
// Stage 2: scan bucket counts -> bstart (exclusive, +total at [256]); seed
// the multisplit reservation cursors.
// ---------------------------------------------------------------------------
__global__ __launch_bounds__(256) void bucket_scan_all(
    const int* __restrict__ bhist, int* __restrict__ bstart,
    int* __restrict__ bcur)
{
    const int y = blockIdx.x;
    const int t = threadIdx.x;
    __shared__ int sh[256];
    int v = bhist[(y * NBMAX + t) * 16];
    sh[t] = v;
    __syncthreads();
    for (int off = 1; off < 256; off <<= 1) {
        int x = (t >= off) ? sh[t - off] : 0;
        __syncthreads();
        sh[t] += x;
        __syncthreads();
    }
    int ex = sh[t] - v;
    bstart[y * (NBMAX + 1) + t] = ex;
    if (t == 255) bstart[y * (NBMAX + 1) + 256] = sh[255];
    bcur[y * NBMAX * 16 + t * 16] = ex;
}

// ---------------------------------------------------------------------------
// Stage 3: LDS-staged multisplit into coarse buckets. Entries packed 32-bit:
// (c&511)<<18 | r  (r < 200000 < 2^18). Bucket id kept in a byte array for
// the coalesced flush. One global atomic per (block, nonzero bucket).
// ---------------------------------------------------------------------------
__global__ __launch_bounds__(256) void multisplit_all(
    const int* r0, const int* r1, const int* r2,
    const int* c0, const int* c1, const int* c2,
    int* bcur, unsigned int* p0, unsigned int* p1, unsigned int* p2,
    int E0, int E1, int E2)
{
    const int y = blockIdx.y;
    const int E = SEL3(y, E0, E1, E2);
    const int base = blockIdx.x * CHUNK;
    if (base >= E) return;
    const int* row = SEL3(y, r0, r1, r2);
    const int* col = SEL3(y, c0, c1, c2);
    int* bc = bcur + y * (NBMAX * 16);
    unsigned int* part = SEL3(y, p0, p1, p2);

    __shared__ int hist[NBMAX];
    __shared__ int segoff[NBMAX + 1];
    __shared__ int cur[NBMAX];
    __shared__ int delta[NBMAX];
    __shared__ unsigned int stage[CHUNK];
    __shared__ unsigned char bstage[CHUNK];

    const int t = threadIdx.x;
    const int n = min(CHUNK, E - base);

    hist[t] = 0;
    __syncthreads();
    for (int i = t; i < n; i += 256)
        atomicAdd(&hist[col[base + i] >> 9], 1);
    __syncthreads();

    int v = hist[t];
    cur[t] = v;
    __syncthreads();
    for (int off = 1; off < 256; off <<= 1) {
        int x = (t >= off) ? cur[t - off] : 0;
        __syncthreads();
        cur[t] += x;
        __syncthreads();
    }
    segoff[t + 1] = cur[t];
    if (t == 0) segoff[0] = 0;
    __syncthreads();
    int so = segoff[t];
    cur[t] = so;
    if (v > 0) {
        int g = atomicAdd(&bc[t * 16], v);
        delta[t] = g - so;
    }
    __syncthreads();

    for (int i = t; i < n; i += 256) {
        int c = col[base + i];
        int r = row[base + i];
        int b = c >> 9;
        int p = atomicAdd(&cur[b], 1);
        stage[p] = ((unsigned)(c & 511) << 18) | (unsigned)r;
        bstage[p] = (unsigned char)b;
    }
    __syncthreads();

    for (int i = t; i < n; i += 256) {
        int b = bstage[i];
        part[delta[b] + i] = stage[i];
    }
}

// ---------------------------------------------------------------------------
// Stage 4: per-bucket CSR finalize. LDS 512-histogram of the bucket's
// partition segment -> LDS scan -> streaming-coalesced deg/excl writes ->
// LDS-cursor fill of esrc (4B stores confined to the bucket's ~window).
// ---------------------------------------------------------------------------
__global__ __launch_bounds__(256) void bucket_csr_all(
    const unsigned int* p0, const unsigned int* p1, const unsigned int* p2,
    const int* __restrict__ bstart,
    int* g0, int* g1, int* g2, int* x0, int* x1, int* x2,
    int* s0, int* s1, int* s2, int n0, int n1, int n2)
{
    const int y = blockIdx.y;
    const int n_dst = SEL3(y, n0, n1, n2);
    const int b = blockIdx.x;
    const int d0 = b * DRC;
    if (d0 >= n_dst) return;
    const unsigned int* part = SEL3(y, p0, p1, p2);
    const int* bs = bstart + y * (NBMAX + 1);
    int* deg  = SEL3(y, g0, g1, g2);
    int* excl = SEL3(y, x0, x1, x2);
    int* esrc = SEL3(y, s0, s1, s2);

    __shared__ int h[DRC];
    __shared__ int cur2[DRC];
    __shared__ int tsum[256];
    const int t = threadIdx.x;
    h[t] = 0; h[t + 256] = 0;
    __syncthreads();
    const int wstart = bs[b], wend = bs[b + 1];
    for (int i = wstart + t; i < wend; i += 256)
        atomicAdd(&h[part[i] >> 18], 1);
    __syncthreads();

    // scan 512 values: pair-sum + Hillis-Steele over 256
    int h0 = h[2 * t], h1 = h[2 * t + 1];
    int ps = h0 + h1;
    tsum[t] = ps;
    __syncthreads();
    for (int off = 1; off < 256; off <<= 1) {
        int x = (t >= off) ? tsum[t - off] : 0;
        __syncthreads();
        tsum[t] += x;
        __syncthreads();
    }
    int exp_ = tsum[t] - ps;
    cur2[2 * t]     = wstart + exp_;
    cur2[2 * t + 1] = wstart + exp_ + h0;
    __syncthreads();

    // coalesced deg/excl writes (replaces the global-atomic deg histogram)
    for (int j = t; j < DRC; j += 256) {
        int d = d0 + j;
        if (d < n_dst) { deg[d] = h[j]; excl[d] = cur2[j]; }
    }
    __syncthreads();

    for (int i = wstart + t; i < wend; i += 256) {
        unsigned int v = part[i];
        int pos = atomicAdd(&cur2[v >> 18], 1);
        esrc[pos] = (int)(v & 0x3FFFFu);
    }
}

// ---------------------------------------------------------------------------
// Gather-mean, 2 rows per load instruction: wave splits 32+32 (sub = edge
// parity); lane owns a 16B (K=256) / 8B (K=128) channel slice.
// ---------------------------------------------------------------------------
template<int LOGK>
__global__ __launch_bounds__(256) void gather_mean(
    const unsigned short* __restrict__ xsrc, const int* __restrict__ esrc,
    const int* __restrict__ start, const int* __restrict__ deg,
    unsigned short* __restrict__ agg, int n_dst)
{
    const int wid = (blockIdx.x * 256 + threadIdx.x) >> 6;
    const int lane = threadIdx.x & 63;
    if (wid >= n_dst) return;
    const int sub = lane >> 5;
    const int cl  = lane & 31;
    const int s = start[wid];
    const int d = deg[wid];
    const float inv = 1.0f / (float)max(d, 1);

    if (LOGK == 7) {
        float a0 = 0, a1 = 0, a2 = 0, a3 = 0;
        const size_t coff = (size_t)cl * 4;
        int i = 0;
        for (; i + 8 <= d; i += 8) {
            int e0 = esrc[s + i + 0 + sub], e1 = esrc[s + i + 2 + sub];
            int e2 = esrc[s + i + 4 + sub], e3 = esrc[s + i + 6 + sub];
            uint2 v0 = *(const uint2*)&xsrc[((size_t)e0 << 7) + coff];
            uint2 v1 = *(const uint2*)&xsrc[((size_t)e1 << 7) + coff];
            uint2 v2 = *(const uint2*)&xsrc[((size_t)e2 << 7) + coff];
            uint2 v3 = *(const uint2*)&xsrc[((size_t)e3 << 7) + coff];
            a0 += b2f_lo(v0.x) + b2f_lo(v1.x) + b2f_lo(v2.x) + b2f_lo(v3.x);
            a1 += b2f_hi(v0.x) + b2f_hi(v1.x) + b2f_hi(v2.x) + b2f_hi(v3.x);
            a2 += b2f_lo(v0.y) + b2f_lo(v1.y) + b2f_lo(v2.y) + b2f_lo(v3.y);
            a3 += b2f_hi(v0.y) + b2f_hi(v1.y) + b2f_hi(v2.y) + b2f_hi(v3.y);
        }
        for (; i + 2 <= d; i += 2) {
            int e0 = esrc[s + i + sub];
            uint2 v0 = *(const uint2*)&xsrc[((size_t)e0 << 7) + coff];
            a0 += b2f_lo(v0.x); a1 += b2f_hi(v0.x);
            a2 += b2f_lo(v0.y); a3 += b2f_hi(v0.y);
        }
        if (i < d && sub == 0) {
            int e0 = esrc[s + i];
            uint2 v0 = *(const uint2*)&xsrc[((size_t)e0 << 7) + coff];
            a0 += b2f_lo(v0.x); a1 += b2f_hi(v0.x);
            a2 += b2f_lo(v0.y); a3 += b2f_hi(v0.y);
        }
        a0 += __shfl_xor(a0, 32); a1 += __shfl_xor(a1, 32);
        a2 += __shfl_xor(a2, 32); a3 += __shfl_xor(a3, 32);
        if (sub == 0) {
            uint2 o;
            o.x = pack2(a0 * inv, a1 * inv);
            o.y = pack2(a2 * inv, a3 * inv);
            *(uint2*)&agg[((size_t)wid << 7) + coff] = o;
        }
    } else {
        float a0 = 0, a1 = 0, a2 = 0, a3 = 0, a4 = 0, a5 = 0, a6 = 0, a7 = 0;
        const size_t coff = (size_t)cl * 8;
        int i = 0;
        for (; i + 8 <= d; i += 8) {
            int e0 = esrc[s + i + 0 + sub], e1 = esrc[s + i + 2 + sub];
            int e2 = esrc[s + i + 4 + sub], e3 = esrc[s + i + 6 + sub];
            uint4 v0 = *(const uint4*)&xsrc[((size_t)e0 << 8) + coff];
            uint4 v1 = *(const uint4*)&xsrc[((size_t)e1 << 8) + coff];
            uint4 v2 = *(const uint4*)&xsrc[((size_t)e2 << 8) + coff];
            uint4 v3 = *(const uint4*)&xsrc[((size_t)e3 << 8) + coff];
            a0 += b2f_lo(v0.x) + b2f_lo(v1.x) + b2f_lo(v2.x) + b2f_lo(v3.x);
            a1 += b2f_hi(v0.x) + b2f_hi(v1.x) + b2f_hi(v2.x) + b2f_hi(v3.x);
            a2 += b2f_lo(v0.y) + b2f_lo(v1.y) + b2f_lo(v2.y) + b2f_lo(v3.y);
            a3 += b2f_hi(v0.y) + b2f_hi(v1.y) + b2f_hi(v2.y) + b2f_hi(v3.y);
            a4 += b2f_lo(v0.z) + b2f_lo(v1.z) + b2f_lo(v2.z) + b2f_lo(v3.z);
            a5 += b2f_hi(v0.z) + b2f_hi(v1.z) + b2f_hi(v2.z) + b2f_hi(v3.z);
            a6 += b2f_lo(v0.w) + b2f_lo(v1.w) + b2f_lo(v2.w) + b2f_lo(v3.w);
            a7 += b2f_hi(v0.w) + b2f_hi(v1.w) + b2f_hi(v2.w) + b2f_hi(v3.w);
        }
        for (; i + 2 <= d; i += 2) {
            int e0 = esrc[s + i + sub];
            uint4 v0 = *(const uint4*)&xsrc[((size_t)e0 << 8) + coff];
            a0 += b2f_lo(v0.x); a1 += b2f_hi(v0.x);
            a2 += b2f_lo(v0.y); a3 += b2f_hi(v0.y);
            a4 += b2f_lo(v0.z); a5 += b2f_hi(v0.z);
            a6 += b2f_lo(v0.w); a7 += b2f_hi(v0.w);
        }
        if (i < d && sub == 0) {
            int e0 = esrc[s + i];
            uint4 v0 = *(const uint4*)&xsrc[((size_t)e0 << 8) + coff];
            a0 += b2f_lo(v0.x); a1 += b2f_hi(v0.x);
            a2 += b2f_lo(v0.y); a3 += b2f_hi(v0.y);
            a4 += b2f_lo(v0.z); a5 += b2f_hi(v0.z);
            a6 += b2f_lo(v0.w); a7 += b2f_hi(v0.w);
        }
        a0 += __shfl_xor(a0, 32); a1 += __shfl_xor(a1, 32);
        a2 += __shfl_xor(a2, 32); a3 += __shfl_xor(a3, 32);
        a4 += __shfl_xor(a4, 32); a5 += __shfl_xor(a5, 32);
        a6 += __shfl_xor(a6, 32); a7 += __shfl_xor(a7, 32);
        if (sub == 0) {
            uint4 o;
            o.x = pack2(a0 * inv, a1 * inv);
            o.y = pack2(a2 * inv, a3 * inv);
            o.z = pack2(a4 * inv, a5 * inv);
            o.w = pack2(a6 * inv, a7 * inv);
            *(uint4*)&agg[((size_t)wid << 8) + coff] = o;
        }
    }
}

// ---------------------------------------------------------------------------
// bf16 MFMA GEMM: h = relu((agg.Wl^T + xdst.Wr^T) * BN_SCALE * g + b), bf16 out
// Block: 512 threads = 8 waves (2 M-halves x 4 N-quarters). Tile 128 x 256.
// ---------------------------------------------------------------------------
template<int KH>
__global__ __launch_bounds__(512) void sage_gemm_mfma(
    const unsigned short* __restrict__ aggb, const unsigned short* __restrict__ xdstb,
    const unsigned short* __restrict__ Wlb, const unsigned short* __restrict__ Wrb,
    const float* __restrict__ g, const float* __restrict__ b,
    unsigned short* __restrict__ h, int n_dst)
{
    __shared__ uint4 A_sh[512];    // [m:128][g':4]
    __shared__ uint4 B_sh[1024];   // [n:256][g':4]

    const int tid  = threadIdx.x;
    const int lane = tid & 63;
    const int wv   = tid >> 6;
    const int mh   = wv >> 2;
    const int n0   = (wv & 3) * 64;
    const int m0g  = blockIdx.x * 128;
    const int lrow = lane & 15;
    const int lgrp = lane >> 4;

    f32x4 acc[4][4];
#pragma unroll
    for (int i = 0; i < 4; ++i)
#pragma unroll
        for (int j = 0; j < 4; ++j)
            acc[i][j] = (f32x4){0.f, 0.f, 0.f, 0.f};

    for (int kp = 0; kp < 2 * KH; kp += 32) {
        const unsigned short* Asrc = (kp < KH) ? aggb : xdstb;
        const unsigned short* Bsrc = (kp < KH) ? Wlb : Wrb;
        const int kbase = (kp < KH) ? kp : kp - KH;

        {
            int m = tid >> 2, gq = tid & 3;
            int r = m0g + m;
            uint4 v = {0, 0, 0, 0};
            if (r < n_dst) v = *(const uint4*)&Asrc[(size_t)r * KH + kbase + gq * 8];
            A_sh[m * 4 + (gq ^ ((m >> 1) & 3))] = v;
        }
        {
            int nb_ = tid >> 2, gq = tid & 3;
#pragma unroll
            for (int i2 = 0; i2 < 2; ++i2) {
                int n = nb_ + 128 * i2;
                uint4 v = *(const uint4*)&Bsrc[(size_t)n * KH + kbase + gq * 8];
                B_sh[n * 4 + (gq ^ ((n >> 1) & 3))] = v;
            }
        }
        __syncthreads();

        short8 av[4], bv[4];
#pragma unroll
        for (int mf = 0; mf < 4; ++mf) {
            int m = mh * 64 + mf * 16 + lrow;
            av[mf] = *reinterpret_cast<const short8*>(&A_sh[m * 4 + (lgrp ^ ((m >> 1) & 3))]);
        }
#pragma unroll
        for (int nf = 0; nf < 4; ++nf) {
            int n = n0 + nf * 16 + lrow;
            bv[nf] = *reinterpret_cast<const short8*>(&B_sh[n * 4 + (lgrp ^ ((n >> 1) & 3))]);
        }
#pragma unroll
        for (int mf = 0; mf < 4; ++mf)
#pragma unroll
            for (int nf = 0; nf < 4; ++nf)
                acc[mf][nf] = __builtin_amdgcn_mfma_f32_16x16x32_bf16(
                    av[mf], bv[nf], acc[mf][nf], 0, 0, 0);
        __syncthreads();
    }

    // epilogue: BN + ReLU, bf16 store. C/D: col=lane&15, row=(lane>>4)*4+reg.
#pragma unroll
    for (int nf = 0; nf < 4; ++nf) {
        int n = n0 + nf * 16 + lrow;
        float sc = g[n] * BN_SCALE;
        float bi = b[n];
#pragma unroll
        for (int mf = 0; mf < 4; ++mf) {
            int mbase = m0g + mh * 64 + mf * 16 + lgrp * 4;
#pragma unroll
            for (int r = 0; r < 4; ++r) {
                int m = mbase + r;
                if (m < n_dst) {
                    float vv = fmaxf(acc[mf][nf][r] * sc + bi, 0.f);
                    h[(size_t)m * HID + n] = f2b1(vv);
                }
            }
        }
    }
}

// ---------------------------------------------------------------------------
// Final layer via MFMA: z = [h0|h1|h2][:25000] @ WlinPad.T + blin (N padded
// to 64), fused log_softmax, fp32 out. Tile 128 x 64, 4 waves.
// ---------------------------------------------------------------------------
__global__ __launch_bounds__(256) void final_mfma(
    const unsigned short* __restrict__ h0, const unsigned short* __restrict__ h1,
    const unsigned short* __restrict__ h2, const unsigned short* __restrict__ wlinb,
    const float* __restrict__ blin, float* __restrict__ out)
{
    __shared__ uint4 A_sh[512];   // [m:128][g':4]
    __shared__ uint4 B_sh[256];   // [n:64][g':4]

    const int tid  = threadIdx.x;
    const int lane = tid & 63;
    const int wv   = tid >> 6;
    const int m0g  = blockIdx.x * 128;
    const int lrow = lane & 15;
    const int lgrp = lane >> 4;

    f32x4 acc[2][4];
#pragma unroll
    for (int i = 0; i < 2; ++i)
#pragma unroll
        for (int j = 0; j < 4; ++j)
            acc[i][j] = (f32x4){0.f, 0.f, 0.f, 0.f};

    for (int kp = 0; kp < 768; kp += 32) {
        const int seg = kp >> 8;
        const unsigned short* hs = (seg == 0) ? h0 : (seg == 1) ? h1 : h2;
        const int kseg = kp & 255;

#pragma unroll
        for (int l = 0; l < 2; ++l) {
            int idx = tid + l * 256;
            int m = idx >> 2, gq = idx & 3;
            int r = m0g + m;
            uint4 v = {0, 0, 0, 0};
            if (r < ENDR) v = *(const uint4*)&hs[(size_t)r * HID + kseg + gq * 8];
            A_sh[m * 4 + (gq ^ ((m >> 1) & 3))] = v;
        }
        {
            int n = tid >> 2, gq = tid & 3;
            uint4 v = *(const uint4*)&wlinb[(size_t)n * 768 + kp + gq * 8];
            B_sh[n * 4 + (gq ^ ((n >> 1) & 3))] = v;
        }
        __syncthreads();

        short8 av[2], bv[4];
#pragma unroll
        for (int mf = 0; mf < 2; ++mf) {
            int m = wv * 32 + mf * 16 + lrow;
            av[mf] = *reinterpret_cast<const short8*>(&A_sh[m * 4 + (lgrp ^ ((m >> 1) & 3))]);
        }
#pragma unroll
        for (int nf = 0; nf < 4; ++nf) {
            int n = nf * 16 + lrow;
            bv[nf] = *reinterpret_cast<const short8*>(&B_sh[n * 4 + (lgrp ^ ((n >> 1) & 3))]);
        }
#pragma unroll
        for (int mf = 0; mf < 2; ++mf)
#pragma unroll
            for (int nf = 0; nf < 4; ++nf)
                acc[mf][nf] = __builtin_amdgcn_mfma_f32_16x16x32_bf16(
                    av[mf], bv[nf], acc[mf][nf], 0, 0, 0);
        __syncthreads();
    }

    float bv4[4];
#pragma unroll
    for (int nf = 0; nf < 4; ++nf) {
        int n = nf * 16 + lrow;
        bv4[nf] = (n < OUTC) ? blin[n] : 0.f;
    }

#pragma unroll
    for (int mf = 0; mf < 2; ++mf) {
        float z[4][4];
        float rmax[4], rsum[4];
#pragma unroll
        for (int r = 0; r < 4; ++r) {
            float mx = -INFINITY;
#pragma unroll
            for (int nf = 0; nf < 4; ++nf) {
                int n = nf * 16 + lrow;
                float v = (n < OUTC) ? acc[mf][nf][r] + bv4[nf] : -INFINITY;
                z[r][nf] = v;
                mx = fmaxf(mx, v);
            }
            rmax[r] = mx;
        }
#pragma unroll
        for (int off = 8; off >= 1; off >>= 1)
#pragma unroll
            for (int r = 0; r < 4; ++r)
                rmax[r] = fmaxf(rmax[r], __shfl_xor(rmax[r], off));
#pragma unroll
        for (int r = 0; r < 4; ++r) {
            float s = 0.f;
#pragma unroll
            for (int nf = 0; nf < 4; ++nf)
                s += (z[r][nf] > -INFINITY) ? expf(z[r][nf] - rmax[r]) : 0.f;
            rsum[r] = s;
        }
#pragma unroll
        for (int off = 8; off >= 1; off >>= 1)
#pragma unroll
            for (int r = 0; r < 4; ++r)
                rsum[r] += __shfl_xor(rsum[r], off);

#pragma unroll
        for (int r = 0; r < 4; ++r) {
            int m = m0g + wv * 32 + mf * 16 + lgrp * 4 + r;
            if (m < ENDR) {
                float lg = rmax[r] + logf(rsum[r]);
#pragma unroll
                for (int nf = 0; nf < 4; ++nf) {
                    int n = nf * 16 + lrow;
                    if (n < OUTC) out[(size_t)m * OUTC + n] = z[r][nf] - lg;
                }
            }
        }
    }
}

// ---------------------------------------------------------------------------
extern "C" void kernel_launch(void* const* d_in, const int* in_sizes, int n_in,
                              void* d_out, int out_size, void* d_ws, size_t ws_size,
                              hipStream_t stream)
{
    const float* x    = (const float*)d_in[0];
    const int* rows[3] = {(const int*)d_in[1], (const int*)d_in[3], (const int*)d_in[5]};
    const int* cols[3] = {(const int*)d_in[2], (const int*)d_in[4], (const int*)d_in[6]};
    const float* Wl[3] = {(const float*)d_in[7],  (const float*)d_in[11], (const float*)d_in[15]};
    const float* Wr[3] = {(const float*)d_in[8],  (const float*)d_in[12], (const float*)d_in[16]};
    const float* gs[3] = {(const float*)d_in[9],  (const float*)d_in[13], (const float*)d_in[17]};
    const float* bs[3] = {(const float*)d_in[10], (const float*)d_in[14], (const float*)d_in[18]};
    const float* Wlin = (const float*)d_in[19];
    const float* blin = (const float*)d_in[20];
    float* out = (float*)d_out;

    const int E0 = in_sizes[1], E1 = in_sizes[3], E2 = in_sizes[5];

    // ----- workspace layout (bytes) -----
    // xb    @ 0          : 51,200,000
    // h0b   @ 51200000   : 51,200,000
    // h1b   @ 102400000  : 25,600,000
    // h2b   @ 128000000  : 12,800,000
    // aggb  @ 140800000  : 25,600,000  (ends 166,400,000)
    // wb    @ 166400000  : 655,360
    // wlinb @ 167100032  : 98,304      (ends 167,198,336)
    // ints  @ 167600000  : esrc0/1/2 | deg0/1/2 | excl0/1/2 | bcur | bhist | bstart
    // part0 @ 181000000  : 6.4 MB; part1 @ 188000000: 3.2; part2 @ 192000000: 1.6
    char* base = (char*)d_ws;
    unsigned short* xb   = (unsigned short*)(base);
    unsigned short* h0b  = (unsigned short*)(base + 51200000);
    unsigned short* h1b  = (unsigned short*)(base + 102400000);
    unsigned short* h2b  = (unsigned short*)(base + 128000000);
    unsigned short* aggb = (unsigned short*)(base + 140800000);
    unsigned short* wb   = (unsigned short*)(base + 166400000);
    unsigned short* wlinb= (unsigned short*)(base + 167100032);
    int* ibase = (int*)(base + 167600000);
    int* esrc0 = ibase;                 // 1.6M
    int* esrc1 = ibase + 1600000;       // 0.8M
    int* esrc2 = ibase + 2400000;       // 0.4M
    int* deg0  = ibase + 2800000;
    int* deg1  = ibase + 2900000;
    int* deg2  = ibase + 2950000;
    int* excl0 = ibase + 3000000;
    int* excl1 = ibase + 3100000;
    int* excl2 = ibase + 3150000;
    int* bcur  = ibase + 3200000;       // 3*NBMAX*16 = 12288
    int* bhist = ibase + 3220000;       // 3*NBMAX*16 = 12288
    int* bstart= ibase + 3240000;       // 3*(NBMAX+1) = 771
    unsigned int* part0 = (unsigned int*)(base + 181000000);
    unsigned int* part1 = (unsigned int*)(base + 188000000);
    unsigned int* part2 = (unsigned int*)(base + 192000000);

    unsigned short* Wlb[3] = {wb,          wb + 65536,  wb + 196608};
    unsigned short* Wrb[3] = {wb + 32768,  wb + 131072, wb + 262144};

    // ----- dtype conversions -----
    f2b_kernel<<<(25600000 / 4 + 255) / 256, 256, 0, stream>>>(x, xb, 25600000);
    hipMemsetAsync(wlinb, 0, 64 * 768 * sizeof(unsigned short), stream);
    f2b_multi<<<356, 256, 0, stream>>>(
        Wl[0], Wr[0], Wl[1], Wr[1], Wl[2], Wr[2], Wlin,
        Wlb[0], Wrb[0], Wlb[1], Wrb[1], Wlb[2], Wrb[2], wlinb);

    // ----- CSR build (4 launches + 1 small memset; no dst-granular global atomics)
    hipMemsetAsync(bhist, 0, 3 * NBMAX * 16 * sizeof(int), stream);
    {
        dim3 gh(128, 3);
        bucket_hist_all<<<gh, 256, 0, stream>>>(
            cols[0], cols[1], cols[2], bhist, E0, E1, E2);
        bucket_scan_all<<<3, 256, 0, stream>>>(bhist, bstart, bcur);
        dim3 gms((E0 + CHUNK - 1) / CHUNK, 3);
        multisplit_all<<<gms, 256, 0, stream>>>(
            rows[0], rows[1], rows[2], cols[0], cols[1], cols[2],
            bcur, part0, part1, part2, E0, E1, E2);
        dim3 gbc((N_DST0 + DRC - 1) / DRC, 3);
        bucket_csr_all<<<gbc, 256, 0, stream>>>(
            part0, part1, part2, bstart,
            deg0, deg1, deg2, excl0, excl1, excl2,
            esrc0, esrc1, esrc2, N_DST0, N_DST1, N_DST2);
    }

    // ----- 3 layers: gather + fused GEMM -----
    const unsigned short* hsrc[3] = {xb, h0b, h1b};
    unsigned short* hdst[3] = {h0b, h1b, h2b};
    int* esrcs[3] = {esrc0, esrc1, esrc2};
    int* excls[3] = {excl0, excl1, excl2};
    int* degs[3]  = {deg0, deg1, deg2};
    const int ndst[3] = {N_DST0, N_DST1, N_DST2};

    for (int L = 0; L < 3; ++L) {
        const int nd = ndst[L];
        if (L == 0) {
            gather_mean<7><<<(nd + 3) / 4, 256, 0, stream>>>(
                hsrc[L], esrcs[L], excls[L], degs[L], aggb, nd);
            sage_gemm_mfma<128><<<(nd + 127) / 128, 512, 0, stream>>>(
                aggb, hsrc[L], Wlb[L], Wrb[L], gs[L], bs[L], hdst[L], nd);
        } else {
            gather_mean<8><<<(nd + 3) / 4, 256, 0, stream>>>(
                hsrc[L], esrcs[L], excls[L], degs[L], aggb, nd);
            sage_gemm_mfma<256><<<(nd + 127) / 128, 512, 0, stream>>>(
                aggb, hsrc[L], Wlb[L], Wrb[L], gs[L], bs[L], hdst[L], nd);
        }
    }

    final_mfma<<<(ENDR + 127) / 128, 256, 0, stream>>>(
        h0b, h1b, h2b, wlinb, blin, out);
}

// Round 10
// 372.899 us; speedup vs baseline: 3.7521x; 1.0890x over previous
//
#include <hip/hip_runtime.h>
#include <hip/hip_bf16.h>

// ---------------------------------------------------------------------------
// JKNet: 3x (bipartite SAGEConv(mean) + BN(eval) + ReLU) -> JK concat -> linear
//        -> log_softmax
// fp16 internal pipeline: CSR via bucket-hist + multisplit counting sort,
// packed-fp16 gather (v_pk_add_f16), fp16 MFMA GEMMs with LDS-staged coalesced
// epilogue (BN/ReLU fused), fused log_softmax final layer.
// ---------------------------------------------------------------------------

#define N_DST0 100000
#define N_DST1 50000
#define N_DST2 25000
#define HID 256
#define OUTC 47
#define ENDR 25000
#define DRC 512                         // dst nodes per coarse bucket
#define NBMAX 256                       // max coarse buckets (100000/512=196)
#define CHUNK 8192                      // edges per multisplit block
#define BN_SCALE 0.99999500003749969f   // rsqrt(1 + 1e-5)

#define SEL3(y, a, b, c) ((y) == 0 ? (a) : ((y) == 1 ? (b) : (c)))

typedef _Float16 f16x8 __attribute__((ext_vector_type(8)));
typedef _Float16 f16x4 __attribute__((ext_vector_type(4)));
typedef __attribute__((ext_vector_type(4))) float f32x4;

__device__ __forceinline__ f16x8 hshfl_add(f16x8 a, int m) {
    union { f16x8 h; int i[4]; } u, v;
    u.h = a;
#pragma unroll
    for (int j = 0; j < 4; ++j) v.i[j] = __shfl_xor(u.i[j], m);
    return a + v.h;
}

// ---------------------------------------------------------------------------
// fp32 -> fp16 conversion (n multiple of 4)
// ---------------------------------------------------------------------------
__global__ __launch_bounds__(256) void f2h_kernel(
    const float* __restrict__ in, _Float16* __restrict__ out, int n)
{
    int i = (blockIdx.x * 256 + threadIdx.x) * 4;
    if (i < n) {
        float4 v = *(const float4*)&in[i];
        f16x4 o = {(_Float16)v.x, (_Float16)v.y, (_Float16)v.z, (_Float16)v.w};
        *(f16x4*)&out[i] = o;
    }
}

// All 7 weight matrices in one launch. Segment boundaries (elements):
// 0,32768,65536,131072,196608,262144,327680,363776 — all multiples of 4.
__global__ __launch_bounds__(256) void f2h_multi(
    const float* s0, const float* s1, const float* s2, const float* s3,
    const float* s4, const float* s5, const float* s6,
    _Float16* d0, _Float16* d1, _Float16* d2, _Float16* d3,
    _Float16* d4, _Float16* d5, _Float16* d6)
{
    int idx = (blockIdx.x * 256 + threadIdx.x) * 4;
    const float* s; _Float16* d; int off;
    if (idx < 65536)       { if (idx < 32768)  { s = s0; d = d0; off = 0; }
                             else              { s = s1; d = d1; off = 32768; } }
    else if (idx < 196608) { if (idx < 131072) { s = s2; d = d2; off = 65536; }
                             else              { s = s3; d = d3; off = 131072; } }
    else if (idx < 327680) { if (idx < 262144) { s = s4; d = d4; off = 196608; }
                             else              { s = s5; d = d5; off = 262144; } }
    else if (idx < 363776) { s = s6; d = d6; off = 327680; }
    else return;
    int j = idx - off;
    float4 v = *(const float4*)&s[j];
    f16x4 o = {(_Float16)v.x, (_Float16)v.y, (_Float16)v.z, (_Float16)v.w};
    *(f16x4*)&d[j] = o;
}

// ---------------------------------------------------------------------------
// Stage 1: coarse-bucket histogram (LDS; one padded global atomic per
// (block, nonzero bucket)).
// ---------------------------------------------------------------------------
__global__ __launch_bounds__(256) void bucket_hist_all(
    const int* c0, const int* c1, const int* c2,
    int* __restrict__ bhist, int E0, int E1, int E2)
{
    const int y = blockIdx.y;
    const int* col = SEL3(y, c0, c1, c2);
    const int E = SEL3(y, E0, E1, E2);
    __shared__ int h[NBMAX];
    const int t = threadIdx.x;
    h[t] = 0;
    __syncthreads();
    const int stride = gridDim.x * 256;
    for (int i = blockIdx.x * 256 + t; i < E; i += stride)
        atomicAdd(&h[col[i] >> 9], 1);
    __syncthreads();
    int v = h[t];
    if (v) atomicAdd(&bhist[(y * NBMAX + t) * 16], v);
}

// ---------------------------------------------------------------------------
// Stage 2: scan bucket counts -> bstart; seed multisplit cursors.
// ---------------------------------------------------------------------------
__global__ __launch_bounds__(256) void bucket_scan_all(
    const int* __restrict__ bhist, int* __restrict__ bstart,
    int* __restrict__ bcur)
{
    const int y = blockIdx.x;
    const int t = threadIdx.x;
    __shared__ int sh[256];
    int v = bhist[(y * NBMAX + t) * 16];
    sh[t] = v;
    __syncthreads();
    for (int off = 1; off < 256; off <<= 1) {
        int x = (t >= off) ? sh[t - off] : 0;
        __syncthreads();
        sh[t] += x;
        __syncthreads();
    }
    int ex = sh[t] - v;
    bstart[y * (NBMAX + 1) + t] = ex;
    if (t == 255) bstart[y * (NBMAX + 1) + 256] = sh[255];
    bcur[y * NBMAX * 16 + t * 16] = ex;
}

// ---------------------------------------------------------------------------
// Stage 3: LDS-staged multisplit; entries packed (c&511)<<18 | r.
// ---------------------------------------------------------------------------
__global__ __launch_bounds__(256) void multisplit_all(
    const int* r0, const int* r1, const int* r2,
    const int* c0, const int* c1, const int* c2,
    int* bcur, unsigned int* p0, unsigned int* p1, unsigned int* p2,
    int E0, int E1, int E2)
{
    const int y = blockIdx.y;
    const int E = SEL3(y, E0, E1, E2);
    const int base = blockIdx.x * CHUNK;
    if (base >= E) return;
    const int* row = SEL3(y, r0, r1, r2);
    const int* col = SEL3(y, c0, c1, c2);
    int* bc = bcur + y * (NBMAX * 16);
    unsigned int* part = SEL3(y, p0, p1, p2);

    __shared__ int hist[NBMAX];
    __shared__ int segoff[NBMAX + 1];
    __shared__ int cur[NBMAX];
    __shared__ int delta[NBMAX];
    __shared__ unsigned int stage[CHUNK];
    __shared__ unsigned char bstage[CHUNK];

    const int t = threadIdx.x;
    const int n = min(CHUNK, E - base);

    hist[t] = 0;
    __syncthreads();
    for (int i = t; i < n; i += 256)
        atomicAdd(&hist[col[base + i] >> 9], 1);
    __syncthreads();

    int v = hist[t];
    cur[t] = v;
    __syncthreads();
    for (int off = 1; off < 256; off <<= 1) {
        int x = (t >= off) ? cur[t - off] : 0;
        __syncthreads();
        cur[t] += x;
        __syncthreads();
    }
    segoff[t + 1] = cur[t];
    if (t == 0) segoff[0] = 0;
    __syncthreads();
    int so = segoff[t];
    cur[t] = so;
    if (v > 0) {
        int g = atomicAdd(&bc[t * 16], v);
        delta[t] = g - so;
    }
    __syncthreads();

    for (int i = t; i < n; i += 256) {
        int c = col[base + i];
        int r = row[base + i];
        int b = c >> 9;
        int p = atomicAdd(&cur[b], 1);
        stage[p] = ((unsigned)(c & 511) << 18) | (unsigned)r;
        bstage[p] = (unsigned char)b;
    }
    __syncthreads();

    for (int i = t; i < n; i += 256) {
        int b = bstage[i];
        part[delta[b] + i] = stage[i];
    }
}

// ---------------------------------------------------------------------------
// Stage 4: per-bucket CSR finalize (LDS hist + scan, coalesced deg/excl,
// LDS-cursor esrc fill).
// ---------------------------------------------------------------------------
__global__ __launch_bounds__(256) void bucket_csr_all(
    const unsigned int* p0, const unsigned int* p1, const unsigned int* p2,
    const int* __restrict__ bstart,
    int* g0, int* g1, int* g2, int* x0, int* x1, int* x2,
    int* s0, int* s1, int* s2, int n0, int n1, int n2)
{
    const int y = blockIdx.y;
    const int n_dst = SEL3(y, n0, n1, n2);
    const int b = blockIdx.x;
    const int d0 = b * DRC;
    if (d0 >= n_dst) return;
    const unsigned int* part = SEL3(y, p0, p1, p2);
    const int* bs = bstart + y * (NBMAX + 1);
    int* deg  = SEL3(y, g0, g1, g2);
    int* excl = SEL3(y, x0, x1, x2);
    int* esrc = SEL3(y, s0, s1, s2);

    __shared__ int h[DRC];
    __shared__ int cur2[DRC];
    __shared__ int tsum[256];
    const int t = threadIdx.x;
    h[t] = 0; h[t + 256] = 0;
    __syncthreads();
    const int wstart = bs[b], wend = bs[b + 1];
    for (int i = wstart + t; i < wend; i += 256)
        atomicAdd(&h[part[i] >> 18], 1);
    __syncthreads();

    int h0 = h[2 * t], h1 = h[2 * t + 1];
    int ps = h0 + h1;
    tsum[t] = ps;
    __syncthreads();
    for (int off = 1; off < 256; off <<= 1) {
        int x = (t >= off) ? tsum[t - off] : 0;
        __syncthreads();
        tsum[t] += x;
        __syncthreads();
    }
    int exp_ = tsum[t] - ps;
    cur2[2 * t]     = wstart + exp_;
    cur2[2 * t + 1] = wstart + exp_ + h0;
    __syncthreads();

    for (int j = t; j < DRC; j += 256) {
        int d = d0 + j;
        if (d < n_dst) { deg[d] = h[j]; excl[d] = cur2[j]; }
    }
    __syncthreads();

    for (int i = wstart + t; i < wend; i += 256) {
        unsigned int v = part[i];
        int pos = atomicAdd(&cur2[v >> 18], 1);
        esrc[pos] = (int)(v & 0x3FFFFu);
    }
}

// ---------------------------------------------------------------------------
// Gather-mean, fp16 packed accumulation. K=128: 16-lane row groups (4 edges
// per load instr); K=256: 32-lane row groups (2 edges per instr). Lane owns
// 16B (8 ch); cross-subgroup merge via shfl; fp32-scaled mean, fp16 out.
// ---------------------------------------------------------------------------
template<int LOGK>
__global__ __launch_bounds__(256) void gather_mean(
    const _Float16* __restrict__ xsrc, const int* __restrict__ esrc,
    const int* __restrict__ start, const int* __restrict__ deg,
    _Float16* __restrict__ agg, int n_dst)
{
    const int wid = (blockIdx.x * 256 + threadIdx.x) >> 6;
    const int lane = threadIdx.x & 63;
    if (wid >= n_dst) return;
    const int s = start[wid];
    const int d = deg[wid];
    const float inv = 1.0f / (float)max(d, 1);
    f16x8 acc = {0, 0, 0, 0, 0, 0, 0, 0};

    if (LOGK == 7) {
        const int sub = lane >> 4;          // 4 subgroups x 16 lanes
        const int cl  = lane & 15;
        const size_t coff = (size_t)cl * 8;
        int i = 0;
        for (; i + 8 <= d; i += 8) {
            int e0 = esrc[s + i + sub], e1 = esrc[s + i + 4 + sub];
            f16x8 v0 = *(const f16x8*)&xsrc[((size_t)e0 << 7) + coff];
            f16x8 v1 = *(const f16x8*)&xsrc[((size_t)e1 << 7) + coff];
            acc += v0;
            acc += v1;
        }
        for (; i + 4 <= d; i += 4) {
            int e0 = esrc[s + i + sub];
            acc += *(const f16x8*)&xsrc[((size_t)e0 << 7) + coff];
        }
        if (i + sub < d) {
            int e0 = esrc[s + i + sub];
            acc += *(const f16x8*)&xsrc[((size_t)e0 << 7) + coff];
        }
        acc = hshfl_add(acc, 16);
        acc = hshfl_add(acc, 32);
        if (sub == 0) {
            f16x8 o;
#pragma unroll
            for (int j = 0; j < 8; ++j) o[j] = (_Float16)((float)acc[j] * inv);
            *(f16x8*)&agg[((size_t)wid << 7) + coff] = o;
        }
    } else {
        const int sub = lane >> 5;          // 2 subgroups x 32 lanes
        const int cl  = lane & 31;
        const size_t coff = (size_t)cl * 8;
        int i = 0;
        for (; i + 8 <= d; i += 8) {
            int e0 = esrc[s + i + sub],     e1 = esrc[s + i + 2 + sub];
            int e2 = esrc[s + i + 4 + sub], e3 = esrc[s + i + 6 + sub];
            f16x8 v0 = *(const f16x8*)&xsrc[((size_t)e0 << 8) + coff];
            f16x8 v1 = *(const f16x8*)&xsrc[((size_t)e1 << 8) + coff];
            f16x8 v2 = *(const f16x8*)&xsrc[((size_t)e2 << 8) + coff];
            f16x8 v3 = *(const f16x8*)&xsrc[((size_t)e3 << 8) + coff];
            acc += v0; acc += v1; acc += v2; acc += v3;
        }
        for (; i + 2 <= d; i += 2) {
            int e0 = esrc[s + i + sub];
            acc += *(const f16x8*)&xsrc[((size_t)e0 << 8) + coff];
        }
        if (i + sub < d) {
            int e0 = esrc[s + i + sub];
            acc += *(const f16x8*)&xsrc[((size_t)e0 << 8) + coff];
        }
        acc = hshfl_add(acc, 32);
        if (sub == 0) {
            f16x8 o;
#pragma unroll
            for (int j = 0; j < 8; ++j) o[j] = (_Float16)((float)acc[j] * inv);
            *(f16x8*)&agg[((size_t)wid << 8) + coff] = o;
        }
    }
}

// ---------------------------------------------------------------------------
// fp16 MFMA GEMM: h = relu((agg.Wl^T + xdst.Wr^T) * BN_SCALE * g + b), fp16 out
// Block: 512 threads = 8 waves (2 M-halves x 4 N-quarters). Tile 128 x 256.
// Epilogue staged through LDS (2 passes of 64 rows) -> coalesced uint4 writes.
// ---------------------------------------------------------------------------
template<int KH>
__global__ __launch_bounds__(512) void sage_gemm_mfma(
    const _Float16* __restrict__ aggb, const _Float16* __restrict__ xdstb,
    const _Float16* __restrict__ Wlb, const _Float16* __restrict__ Wrb,
    const float* __restrict__ g, const float* __restrict__ b,
    _Float16* __restrict__ h, int n_dst)
{
    __shared__ uint4 SH[2176];     // 34,816 B: A[512] | B[1024]; reused as C-stage
    uint4* A_sh = SH;
    uint4* B_sh = SH + 512;

    const int tid  = threadIdx.x;
    const int lane = tid & 63;
    const int wv   = tid >> 6;
    const int mh   = wv >> 2;
    const int n0   = (wv & 3) * 64;
    const int m0g  = blockIdx.x * 128;
    const int lrow = lane & 15;
    const int lgrp = lane >> 4;

    f32x4 acc[4][4];
#pragma unroll
    for (int i = 0; i < 4; ++i)
#pragma unroll
        for (int j = 0; j < 4; ++j)
            acc[i][j] = (f32x4){0.f, 0.f, 0.f, 0.f};

    for (int kp = 0; kp < 2 * KH; kp += 32) {
        const _Float16* Asrc = (kp < KH) ? aggb : xdstb;
        const _Float16* Bsrc = (kp < KH) ? Wlb : Wrb;
        const int kbase = (kp < KH) ? kp : kp - KH;

        {
            int m = tid >> 2, gq = tid & 3;
            int r = m0g + m;
            uint4 v = {0, 0, 0, 0};
            if (r < n_dst) v = *(const uint4*)&Asrc[(size_t)r * KH + kbase + gq * 8];
            A_sh[m * 4 + (gq ^ ((m >> 1) & 3))] = v;
        }
        {
            int nb_ = tid >> 2, gq = tid & 3;
#pragma unroll
            for (int i2 = 0; i2 < 2; ++i2) {
                int n = nb_ + 128 * i2;
                uint4 v = *(const uint4*)&Bsrc[(size_t)n * KH + kbase + gq * 8];
                B_sh[n * 4 + (gq ^ ((n >> 1) & 3))] = v;
            }
        }
        __syncthreads();

        f16x8 av[4], bv[4];
#pragma unroll
        for (int mf = 0; mf < 4; ++mf) {
            int m = mh * 64 + mf * 16 + lrow;
            av[mf] = *reinterpret_cast<const f16x8*>(&A_sh[m * 4 + (lgrp ^ ((m >> 1) & 3))]);
        }
#pragma unroll
        for (int nf = 0; nf < 4; ++nf) {
            int n = n0 + nf * 16 + lrow;
            bv[nf] = *reinterpret_cast<const f16x8*>(&B_sh[n * 4 + (lgrp ^ ((n >> 1) & 3))]);
        }
#pragma unroll
        for (int mf = 0; mf < 4; ++mf)
#pragma unroll
            for (int nf = 0; nf < 4; ++nf)
                acc[mf][nf] = __builtin_amdgcn_mfma_f32_16x16x32_f16(
                    av[mf], bv[nf], acc[mf][nf], 0, 0, 0);
        __syncthreads();
    }

    // Epilogue: BN + ReLU; stage each 64-row half in LDS [64][264] ushorts,
    // then fully-coalesced uint4 row writes. C/D: col=lane&15, row=(lane>>4)*4+reg.
    unsigned short* C_sh = (unsigned short*)SH;
#pragma unroll
    for (int half = 0; half < 2; ++half) {
        __syncthreads();
        if (mh == half) {
#pragma unroll
            for (int nf = 0; nf < 4; ++nf) {
                int n = n0 + nf * 16 + lrow;
                float sc = g[n] * BN_SCALE;
                float bi = b[n];
#pragma unroll
                for (int mf = 0; mf < 4; ++mf) {
                    int mloc = mf * 16 + lgrp * 4;
#pragma unroll
                    for (int r = 0; r < 4; ++r) {
                        float vv = fmaxf(acc[mf][nf][r] * sc + bi, 0.f);
                        _Float16 hv = (_Float16)vv;
                        C_sh[(mloc + r) * 264 + n] = *(unsigned short*)&hv;
                    }
                }
            }
        }
        __syncthreads();
        int mbase = m0g + half * 64;
#pragma unroll
        for (int k = 0; k < 4; ++k) {
            int idx = tid + k * 512;
            int rr = idx >> 5, cc = idx & 31;
            int m = mbase + rr;
            if (m < n_dst)
                *(uint4*)&h[(size_t)m * HID + cc * 8] =
                    *(const uint4*)&C_sh[rr * 264 + cc * 8];
        }
    }
}

// ---------------------------------------------------------------------------
// Final layer via MFMA (fp16 inputs): z = [h0|h1|h2][:25000] @ WlinPad.T +
// blin (N padded to 64), fused log_softmax, fp32 out. Tile 128 x 64, 4 waves.
// ---------------------------------------------------------------------------
__global__ __launch_bounds__(256) void final_mfma(
    const _Float16* __restrict__ h0, const _Float16* __restrict__ h1,
    const _Float16* __restrict__ h2, const _Float16* __restrict__ wlinb,
    const float* __restrict__ blin, float* __restrict__ out)
{
    __shared__ uint4 A_sh[512];   // [m:128][g':4]
    __shared__ uint4 B_sh[256];   // [n:64][g':4]

    const int tid  = threadIdx.x;
    const int lane = tid & 63;
    const int wv   = tid >> 6;
    const int m0g  = blockIdx.x * 128;
    const int lrow = lane & 15;
    const int lgrp = lane >> 4;

    f32x4 acc[2][4];
#pragma unroll
    for (int i = 0; i < 2; ++i)
#pragma unroll
        for (int j = 0; j < 4; ++j)
            acc[i][j] = (f32x4){0.f, 0.f, 0.f, 0.f};

    for (int kp = 0; kp < 768; kp += 32) {
        const int seg = kp >> 8;
        const _Float16* hs = (seg == 0) ? h0 : (seg == 1) ? h1 : h2;
        const int kseg = kp & 255;

#pragma unroll
        for (int l = 0; l < 2; ++l) {
            int idx = tid + l * 256;
            int m = idx >> 2, gq = idx & 3;
            int r = m0g + m;
            uint4 v = {0, 0, 0, 0};
            if (r < ENDR) v = *(const uint4*)&hs[(size_t)r * HID + kseg + gq * 8];
            A_sh[m * 4 + (gq ^ ((m >> 1) & 3))] = v;
        }
        {
            int n = tid >> 2, gq = tid & 3;
            uint4 v = *(const uint4*)&wlinb[(size_t)n * 768 + kp + gq * 8];
            B_sh[n * 4 + (gq ^ ((n >> 1) & 3))] = v;
        }
        __syncthreads();

        f16x8 av[2], bv[4];
#pragma unroll
        for (int mf = 0; mf < 2; ++mf) {
            int m = wv * 32 + mf * 16 + lrow;
            av[mf] = *reinterpret_cast<const f16x8*>(&A_sh[m * 4 + (lgrp ^ ((m >> 1) & 3))]);
        }
#pragma unroll
        for (int nf = 0; nf < 4; ++nf) {
            int n = nf * 16 + lrow;
            bv[nf] = *reinterpret_cast<const f16x8*>(&B_sh[n * 4 + (lgrp ^ ((n >> 1) & 3))]);
        }
#pragma unroll
        for (int mf = 0; mf < 2; ++mf)
#pragma unroll
            for (int nf = 0; nf < 4; ++nf)
                acc[mf][nf] = __builtin_amdgcn_mfma_f32_16x16x32_f16(
                    av[mf], bv[nf], acc[mf][nf], 0, 0, 0);
        __syncthreads();
    }

    float bv4[4];
#pragma unroll
    for (int nf = 0; nf < 4; ++nf) {
        int n = nf * 16 + lrow;
        bv4[nf] = (n < OUTC) ? blin[n] : 0.f;
    }

#pragma unroll
    for (int mf = 0; mf < 2; ++mf) {
        float z[4][4];
        float rmax[4], rsum[4];
#pragma unroll
        for (int r = 0; r < 4; ++r) {
            float mx = -INFINITY;
#pragma unroll
            for (int nf = 0; nf < 4; ++nf) {
                int n = nf * 16 + lrow;
                float v = (n < OUTC) ? acc[mf][nf][r] + bv4[nf] : -INFINITY;
                z[r][nf] = v;
                mx = fmaxf(mx, v);
            }
            rmax[r] = mx;
        }
#pragma unroll
        for (int off = 8; off >= 1; off >>= 1)
#pragma unroll
            for (int r = 0; r < 4; ++r)
                rmax[r] = fmaxf(rmax[r], __shfl_xor(rmax[r], off));
#pragma unroll
        for (int r = 0; r < 4; ++r) {
            float s = 0.f;
#pragma unroll
            for (int nf = 0; nf < 4; ++nf)
                s += (z[r][nf] > -INFINITY) ? expf(z[r][nf] - rmax[r]) : 0.f;
            rsum[r] = s;
        }
#pragma unroll
        for (int off = 8; off >= 1; off >>= 1)
#pragma unroll
            for (int r = 0; r < 4; ++r)
                rsum[r] += __shfl_xor(rsum[r], off);

#pragma unroll
        for (int r = 0; r < 4; ++r) {
            int m = m0g + wv * 32 + mf * 16 + lgrp * 4 + r;
            if (m < ENDR) {
                float lg = rmax[r] + logf(rsum[r]);
#pragma unroll
                for (int nf = 0; nf < 4; ++nf) {
                    int n = nf * 16 + lrow;
                    if (n < OUTC) out[(size_t)m * OUTC + n] = z[r][nf] - lg;
                }
            }
        }
    }
}

// ---------------------------------------------------------------------------
extern "C" void kernel_launch(void* const* d_in, const int* in_sizes, int n_in,
                              void* d_out, int out_size, void* d_ws, size_t ws_size,
                              hipStream_t stream)
{
    const float* x    = (const float*)d_in[0];
    const int* rows[3] = {(const int*)d_in[1], (const int*)d_in[3], (const int*)d_in[5]};
    const int* cols[3] = {(const int*)d_in[2], (const int*)d_in[4], (const int*)d_in[6]};
    const float* Wl[3] = {(const float*)d_in[7],  (const float*)d_in[11], (const float*)d_in[15]};
    const float* Wr[3] = {(const float*)d_in[8],  (const float*)d_in[12], (const float*)d_in[16]};
    const float* gs[3] = {(const float*)d_in[9],  (const float*)d_in[13], (const float*)d_in[17]};
    const float* bs[3] = {(const float*)d_in[10], (const float*)d_in[14], (const float*)d_in[18]};
    const float* Wlin = (const float*)d_in[19];
    const float* blin = (const float*)d_in[20];
    float* out = (float*)d_out;

    const int E0 = in_sizes[1], E1 = in_sizes[3], E2 = in_sizes[5];

    // ----- workspace layout (bytes) — identical sizes to R9 (fp16 = 2B) -----
    char* base = (char*)d_ws;
    _Float16* xb   = (_Float16*)(base);
    _Float16* h0b  = (_Float16*)(base + 51200000);
    _Float16* h1b  = (_Float16*)(base + 102400000);
    _Float16* h2b  = (_Float16*)(base + 128000000);
    _Float16* aggb = (_Float16*)(base + 140800000);
    _Float16* wb   = (_Float16*)(base + 166400000);
    _Float16* wlinb= (_Float16*)(base + 167100032);
    int* ibase = (int*)(base + 167600000);
    int* esrc0 = ibase;                 // 1.6M
    int* esrc1 = ibase + 1600000;       // 0.8M
    int* esrc2 = ibase + 2400000;       // 0.4M
    int* deg0  = ibase + 2800000;
    int* deg1  = ibase + 2900000;
    int* deg2  = ibase + 2950000;
    int* excl0 = ibase + 3000000;
    int* excl1 = ibase + 3100000;
    int* excl2 = ibase + 3150000;
    int* bcur  = ibase + 3200000;       // 3*NBMAX*16 = 12288
    int* bhist = ibase + 3220000;       // 3*NBMAX*16 = 12288
    int* bstart= ibase + 3240000;       // 3*(NBMAX+1) = 771
    unsigned int* part0 = (unsigned int*)(base + 181000000);
    unsigned int* part1 = (unsigned int*)(base + 188000000);
    unsigned int* part2 = (unsigned int*)(base + 192000000);

    _Float16* Wlb[3] = {wb,          wb + 65536,  wb + 196608};
    _Float16* Wrb[3] = {wb + 32768,  wb + 131072, wb + 262144};

    // ----- dtype conversions -----
    f2h_kernel<<<(25600000 / 4 + 255) / 256, 256, 0, stream>>>(x, xb, 25600000);
    hipMemsetAsync(wlinb, 0, 64 * 768 * sizeof(_Float16), stream);
    f2h_multi<<<356, 256, 0, stream>>>(
        Wl[0], Wr[0], Wl[1], Wr[1], Wl[2], Wr[2], Wlin,
        Wlb[0], Wrb[0], Wlb[1], Wrb[1], Wlb[2], Wrb[2], wlinb);

    // ----- CSR build (4 launches + 1 small memset) -----
    hipMemsetAsync(bhist, 0, 3 * NBMAX * 16 * sizeof(int), stream);
    {
        dim3 gh(128, 3);
        bucket_hist_all<<<gh, 256, 0, stream>>>(
            cols[0], cols[1], cols[2], bhist, E0, E1, E2);
        bucket_scan_all<<<3, 256, 0, stream>>>(bhist, bstart, bcur);
        dim3 gms((E0 + CHUNK - 1) / CHUNK, 3);
        multisplit_all<<<gms, 256, 0, stream>>>(
            rows[0], rows[1], rows[2], cols[0], cols[1], cols[2],
            bcur, part0, part1, part2, E0, E1, E2);
        dim3 gbc((N_DST0 + DRC - 1) / DRC, 3);
        bucket_csr_all<<<gbc, 256, 0, stream>>>(
            part0, part1, part2, bstart,
            deg0, deg1, deg2, excl0, excl1, excl2,
            esrc0, esrc1, esrc2, N_DST0, N_DST1, N_DST2);
    }

    // ----- 3 layers: gather + fused GEMM -----
    const _Float16* hsrc[3] = {xb, h0b, h1b};
    _Float16* hdst[3] = {h0b, h1b, h2b};
    int* esrcs[3] = {esrc0, esrc1, esrc2};
    int* excls[3] = {excl0, excl1, excl2};
    int* degs[3]  = {deg0, deg1, deg2};
    const int ndst[3] = {N_DST0, N_DST1, N_DST2};

    for (int L = 0; L < 3; ++L) {
        const int nd = ndst[L];
        if (L == 0) {
            gather_mean<7><<<(nd + 3) / 4, 256, 0, stream>>>(
                hsrc[L], esrcs[L], excls[L], degs[L], aggb, nd);
            sage_gemm_mfma<128><<<(nd + 127) / 128, 512, 0, stream>>>(
                aggb, hsrc[L], Wlb[L], Wrb[L], gs[L], bs[L], hdst[L], nd);
        } else {
            gather_mean<8><<<(nd + 3) / 4, 256, 0, stream>>>(
                hsrc[L], esrcs[L], excls[L], degs[L], aggb, nd);
            sage_gemm_mfma<256><<<(nd + 127) / 128, 512, 0, stream>>>(
                aggb, hsrc[L], Wlb[L], Wrb[L], gs[L], bs[L], hdst[L], nd);
        }
    }

    final_mfma<<<(ENDR + 127) / 128, 256, 0, stream>>>(
        h0b, h1b, h2b, wlinb, blin, out);
}